// Round 9
// baseline (28537.039 us; speedup 1.0000x reference)
//
#include <hip/hip_runtime.h>
#include <hip/hip_cooperative_groups.h>
#include <math.h>
#include <stdint.h>

namespace cg = cooperative_groups;

// ---------------------------------------------------------------------------
// DualSpectralDiffusion: faithful replication of the JAX reference.
//  - f64 eigh: persistent multi-block sytd2 (A in LDS, NB=16 blocks/matrix)
//    for columns 0..383 + single-block tail; D&C w/ slaed2 deflation mimicry.
//  - exact threefry2x32 / jax.random replication (PARTITIONABLE stream)
//  - diffusion: ONE cooperative kernel (512 blocks = 2/CU, same tiling as
//    the proven split k_gemm32; grid.sync() replaces 300 kernel boundaries;
//    per-element accumulation order identical -> bit-identical). Host
//    fallback to the split pipeline if cooperative launch is rejected.
// ---------------------------------------------------------------------------

#define NT 256
#define SZF 131072          // 512*256 floats per (b) tensor
#define MATSZ 262144        // 512*512
#define NB 16               // sytd2 blocks per matrix (32 rows each, in LDS)
#define ILAST 384           // persistent kernel handles i in [0,ILAST)
#define TBASE (ILAST+1)     // 385
#define TSZ (512-TBASE)     // 127

// bisect scratch layout (double offsets from bscr), 8 slots everywhere
#define BD_DK   0
#define BD_ZK   4096
#define BD_RZK  8192
#define BD_TAU  12288
#define BD_DS   16384
#define BD_RHO  20480
#define BD_KSK  20736
#define BD_KIDX 22784
#define BD_DIDX 24832
#define BD_PERM 26880
#define BD_CNT  28928

#define ALD(p)    __hip_atomic_load((p),  __ATOMIC_RELAXED, __HIP_MEMORY_SCOPE_AGENT)
#define AST(p,v)  __hip_atomic_store((p), (v), __ATOMIC_RELAXED, __HIP_MEMORY_SCOPE_AGENT)

// ----------------------------- threefry ------------------------------------
__host__ __device__ static inline unsigned rotl32(unsigned v, int r){ return (v<<r)|(v>>(32-r)); }

__host__ __device__ static inline void tf2x32(unsigned k0, unsigned k1,
                                              unsigned x0, unsigned x1,
                                              unsigned* o0, unsigned* o1){
  unsigned ks2 = k0 ^ k1 ^ 0x1BD11BDAu;
  x0 += k0; x1 += k1;
#define TF4(r0,r1,r2,r3) \
  x0 += x1; x1 = rotl32(x1,r0); x1 ^= x0; \
  x0 += x1; x1 = rotl32(x1,r1); x1 ^= x0; \
  x0 += x1; x1 = rotl32(x1,r2); x1 ^= x0; \
  x0 += x1; x1 = rotl32(x1,r3); x1 ^= x0;
  TF4(13,15,26,6)  x0 += k1;  x1 += ks2 + 1u;
  TF4(17,29,16,24) x0 += ks2; x1 += k0 + 2u;
  TF4(13,15,26,6)  x0 += k0;  x1 += k1 + 3u;
  TF4(17,29,16,24) x0 += k1;  x1 += ks2 + 4u;
  TF4(13,15,26,6)  x0 += ks2; x1 += k0 + 5u;
#undef TF4
  *o0 = x0; *o1 = x1;
}

// XLA ErfInv f32 polynomial; matches lax.erf_inv expansion.
__device__ static inline float erfinv_xla(float x){
  float w = -log1pf(-x*x);
  float p;
  if (w < 5.0f){
    w -= 2.5f;
    p = 2.81022636e-08f;
    p = fmaf(p, w, 3.43273939e-07f);
    p = fmaf(p, w, -3.5233877e-06f);
    p = fmaf(p, w, -4.39150654e-06f);
    p = fmaf(p, w, 0.00021858087f);
    p = fmaf(p, w, -0.00125372503f);
    p = fmaf(p, w, -0.00417768164f);
    p = fmaf(p, w, 0.246640727f);
    p = fmaf(p, w, 1.50140941f);
  } else {
    w = sqrtf(w) - 3.0f;
    p = -0.000200214257f;
    p = fmaf(p, w, 0.000100950558f);
    p = fmaf(p, w, 0.00134934322f);
    p = fmaf(p, w, -0.00367342844f);
    p = fmaf(p, w, 0.00573950773f);
    p = fmaf(p, w, -0.0076224613f);
    p = fmaf(p, w, 0.00943887047f);
    p = fmaf(p, w, 1.00167406f);
    p = fmaf(p, w, 2.83297682f);
  }
  return p*x;
}

__device__ static inline float bits_to_normal(unsigned bits){
  const float MINV = -0.99999994f;   // nextafter(-1,0) in f32
  float f = __uint_as_float((bits >> 9) | 0x3f800000u) - 1.0f;
  float u = fmaxf(MINV, fmaf(f, 2.0f, MINV));
  return 1.41421356237309515f * erfinv_xla(u);
}

// ------------------------------- eigh --------------------------------------
// Persistent multi-block Householder head: columns 0..ILAST-1.
__global__ __launch_bounds__(256) void k_sytd2_lds(const float* Gs, const float* Gt,
                                                   double* Vb, double* smalls,
                                                   unsigned* slots, double* Atail){
  int sg = blockIdx.x / NB, g = blockIdx.x % NB;
  const float* G = (sg < 4) ? (Gs + (size_t)sg*MATSZ) : (Gt + (size_t)(sg-4)*MATSZ);
  double* V = Vb + (size_t)sg*MATSZ;
  double* d  = smalls + (size_t)sg*512;
  double* e  = smalls + 4096 + (size_t)sg*512;
  double* tu = smalls + 8192 + (size_t)sg*512;
  double* acc0 = smalls + 274688 + (size_t)sg*512;
  double* acc1 = acc0 + 4096;
  double* col0 = smalls + 282880 + (size_t)sg*512;
  double* col1 = col0 + 4096;
  double* vvh  = smalls + 291072 + (size_t)sg*512;
  double* At = Atail + (size_t)sg*MATSZ;
  int t = threadIdx.x, wave = t >> 6, lane = t & 63;

  __shared__ double Arows[32][512];   // owned rows r = 16*j + g
  __shared__ double vv[512], wv[512], col2[512], acc[512];
  __shared__ double red[4];
  __shared__ double bc[4];
  __shared__ int sdead;

  if (t == 0) sdead = 0;

  for (int j=0; j<32; j++){
    int r = NB*j + g;
    for (int c=t; c<512; c+=256)
      Arows[j][c] = (double)G[(size_t)r*512 + c];
  }

  // ---------- init: reflector 0 (replicated) ----------
  for (int r=t; r<512; r+=256) col2[r] = (r>=1) ? (double)G[(size_t)r*512] : 0.0;
  __syncthreads();
  {
    double part = 0.0;
    for (int r=2+t; r<512; r+=256) part += col2[r]*col2[r];
    #pragma unroll
    for (int off=32; off; off>>=1) part += __shfl_down(part, off, 64);
    if (lane==0) red[wave]=part;
    __syncthreads();
    if (t==0){
      double xsq = red[0]+red[1]+red[2]+red[3];
      double alpha = col2[1];
      double beta,tv,scal;
      if (xsq == 0.0){ beta=alpha; tv=0.0; scal=0.0; }
      else {
        beta = -copysign(sqrt(alpha*alpha + xsq), alpha);   // LAPACK slarfg
        tv = (beta - alpha)/beta;
        scal = 1.0/(alpha - beta);
      }
      if (g==0){ e[0]=beta; tu[0]=tv; }
      bc[0]=tv; bc[1]=scal;
    }
  }
  __syncthreads();
  double tauv = bc[0];
  {
    double scal = bc[1];
    for (int r=t; r<512; r+=256){
      double v = 0.0;
      if (r==1) v = 1.0;
      else if (r>1) v = (tauv==0.0) ? 0.0 : col2[r]*scal;
      vv[r]=v;
      if (r>=1 && (r & (NB-1))==g) V[r] = v;
    }
  }
  __syncthreads();
  if (g==0){
    for (int r=1+t; r<512; r+=256) AST(&col0[r], (double)G[(size_t)r*512 + 1]);
  }
  {
    int r0 = 1 + ((g - 1) & (NB-1));
    for (int r = r0 + NB*wave; r < 512; r += 4*NB){
      const double* Ar = Arows[r>>4];
      double p = 0.0;
      for (int c=lane; c<512; c+=64) p += Ar[c]*vv[c];
      #pragma unroll
      for (int off=32; off; off>>=1) p += __shfl_down(p, off, 64);
      if (lane==0) AST(&acc0[r], p);
    }
  }
  __syncthreads();                    // drain init publishes
  if (t == 0) AST(slots + (sg*NB + g)*16, 1u);   // publish #0 done

  // ---------- main loop (fused phases), i in [0, ILAST) ----------
  for (int i=0; i<ILAST; i++){
    if (t < NB && !sdead){
      unsigned* sl = slots + (sg*NB + t)*16;
      int spins = 0;
      while (ALD(sl) < (unsigned)(i+1)){
        if (++spins > (1<<24)){ sdead = 1; break; }
        if ((spins & 3) == 0) __builtin_amdgcn_s_sleep(1);
      }
    }
    __syncthreads();
    int lo=i+1, lo2=i+2;
    double* accR = (i&1) ? acc1 : acc0;
    double* colR = (i&1) ? col1 : col0;
    double* accW = (i&1) ? acc0 : acc1;
    double* colW = (i&1) ? col0 : col1;
    double part = 0.0;
    for (int r=lo+t; r<512; r+=256){
      double a_ = ALD(&accR[r]);
      double c_ = ALD(&colR[r]);
      acc[r]=a_; col2[r]=c_;
      part += (tauv*a_)*vv[r];
    }
    #pragma unroll
    for (int off=32; off; off>>=1) part += __shfl_down(part, off, 64);
    if (lane==0) red[wave]=part;
    __syncthreads();                                   // S1
    {
      double dot = red[0]+red[1]+red[2]+red[3];
      double alpha2 = -0.5*tauv*dot;
      double vlo = vv[lo];
      double wlo = fma(alpha2, vlo, tauv*acc[lo]);
      for (int r=lo+t; r<512; r+=256){
        double wr = fma(alpha2, vv[r], tauv*acc[r]);
        wv[r]=wr;
        col2[r] = col2[r] - vv[r]*wlo - wr*vlo;
      }
    }
    __syncthreads();                                   // S2
    part = 0.0;
    for (int r=lo2+1+t; r<512; r+=256) part += col2[r]*col2[r];
    #pragma unroll
    for (int off=32; off; off>>=1) part += __shfl_down(part, off, 64);
    if (lane==0) red[wave]=part;
    __syncthreads();                                   // S3
    double tau2, scal2;
    {
      double xsq = red[0]+red[1]+red[2]+red[3];
      double alpha = col2[lo2];
      double beta;
      if (xsq == 0.0){ beta=alpha; tau2=0.0; scal2=0.0; }
      else {
        beta = -copysign(sqrt(alpha*alpha + xsq), alpha);
        tau2 = (beta - alpha)/beta;
        scal2 = 1.0/(alpha - beta);
      }
      if (t==0 && g==0){ e[lo]=beta; tu[lo]=tau2; }
    }
    {
      double vvc[8], wvc[8], v2c[8];
      #pragma unroll
      for (int j=0;j<8;j++){
        int c = lo + lane + 64*j;
        bool ok = c < 512;
        vvc[j] = ok ? vv[c] : 0.0;
        wvc[j] = ok ? wv[c] : 0.0;
        double v2v = 0.0;
        if (ok){
          if (c==lo2) v2v = 1.0;
          else if (c>lo2) v2v = (tau2==0.0) ? 0.0 : col2[c]*scal2;
        }
        v2c[j] = v2v;
      }
      int r0 = lo + ((g - lo) & (NB-1));
      for (int r = r0 + NB*wave; r < 512; r += 4*NB){
        double* Ar = Arows[r>>4];
        double vr = vv[r], wr = wv[r];
        double p = 0.0;
        #pragma unroll
        for (int j=0;j<8;j++){
          int c = lo + lane + 64*j;
          if (c < 512){
            double an = Ar[c] - vr*wvc[j] - wr*vvc[j];
            Ar[c] = an;
            p += an * v2c[j];
            if (c == lo2) AST(&colW[r], an);
          }
        }
        #pragma unroll
        for (int off=32; off; off>>=1) p += __shfl_down(p, off, 64);
        if (lane==0) AST(&accW[r], p);
      }
    }
    __syncthreads();                                   // S4 (drains ASTs)
    if (t == 0) AST(slots + (sg*NB + g)*16, (unsigned)(i+2));  // early publish
    for (int r=t; r<512; r+=256){
      double v = 0.0;
      if (r==lo2) v = 1.0;
      else if (r>lo2) v = (tau2==0.0) ? 0.0 : col2[r]*scal2;
      vv[r]=v;
      if (r>=lo2 && (r & (NB-1))==g) V[(size_t)lo*512 + r] = v;
    }
    tauv = tau2;
  }

  // ---------- handoff ----------
  if (t < 32){
    int r = NB*t + g;
    if (r <= ILAST) d[r] = Arows[t][r];
  }
  for (int j=0; j<32; j++){
    int r = NB*j + g;
    if (r >= TBASE){
      for (int c=TBASE+t; c<512; c+=256)
        At[(size_t)r*512 + c] = Arows[j][c];
    }
  }
  if (g==0){
    for (int r=t; r<512; r+=256) vvh[r] = vv[r];
  }
}

// Tail: columns ILAST..509, one block per matrix, A trailing in LDS.
__global__ __launch_bounds__(256) void k_sy_tail(const double* Atail, double* Vb,
                                                 double* smalls){
  int sg = blockIdx.x;
  double* V = Vb + (size_t)sg*MATSZ;
  double* d  = smalls + (size_t)sg*512;
  double* e  = smalls + 4096 + (size_t)sg*512;
  double* tu = smalls + 8192 + (size_t)sg*512;
  const double* accG = smalls + 274688 + (size_t)sg*512;  // parity(ILAST)=even -> base
  const double* colG = smalls + 282880 + (size_t)sg*512;
  const double* vvG  = smalls + 291072 + (size_t)sg*512;
  const double* At0 = Atail + (size_t)sg*MATSZ;
  int t = threadIdx.x, wave = t >> 6, lane = t & 63;

  __shared__ double At[TSZ*128];
  __shared__ double vv[512], wv[512], col2[512], acc[512], accN[512], colN[512];
  __shared__ double red[4];

  for (int rl=0; rl<TSZ; rl++)
    for (int cl=t; cl<TSZ; cl+=256)
      At[rl*128+cl] = At0[(size_t)(TBASE+rl)*512 + TBASE+cl];
  for (int r=t; r<512; r+=256){
    if (r >= ILAST){ vv[r]=vvG[r]; acc[r]=accG[r]; col2[r]=colG[r]; }
  }
  double tauv = tu[ILAST];
  __syncthreads();

  for (int i=ILAST; i<510; i++){
    int lo=i+1, lo2=i+2;
    double part = 0.0;
    for (int r=lo+t; r<512; r+=256) part += (tauv*acc[r])*vv[r];
    #pragma unroll
    for (int off=32; off; off>>=1) part += __shfl_down(part, off, 64);
    if (lane==0) red[wave]=part;
    __syncthreads();                                   // S1
    {
      double dot = red[0]+red[1]+red[2]+red[3];
      double alpha2 = -0.5*tauv*dot;
      double vlo = vv[lo];
      double wlo = fma(alpha2, vlo, tauv*acc[lo]);
      for (int r=lo+t; r<512; r+=256){
        double wr = fma(alpha2, vv[r], tauv*acc[r]);
        wv[r]=wr;
        col2[r] = col2[r] - vv[r]*wlo - wr*vlo;
      }
    }
    __syncthreads();                                   // S2
    part = 0.0;
    for (int r=lo2+1+t; r<512; r+=256) part += col2[r]*col2[r];
    #pragma unroll
    for (int off=32; off; off>>=1) part += __shfl_down(part, off, 64);
    if (lane==0) red[wave]=part;
    __syncthreads();                                   // S3
    double tau2, scal2;
    {
      double xsq = red[0]+red[1]+red[2]+red[3];
      double alpha = col2[lo2];
      double beta;
      if (xsq == 0.0){ beta=alpha; tau2=0.0; scal2=0.0; }
      else {
        beta = -copysign(sqrt(alpha*alpha + xsq), alpha);
        tau2 = (beta - alpha)/beta;
        scal2 = 1.0/(alpha - beta);
      }
      if (t==0){ e[lo]=beta; tu[lo]=tau2; }
    }
    {
      double vvc[8], wvc[8], v2c[8];
      #pragma unroll
      for (int j=0;j<8;j++){
        int c = lo + lane + 64*j;
        bool ok = c < 512;
        vvc[j] = ok ? vv[c] : 0.0;
        wvc[j] = ok ? wv[c] : 0.0;
        double v2v = 0.0;
        if (ok){
          if (c==lo2) v2v = 1.0;
          else if (c>lo2) v2v = (tau2==0.0) ? 0.0 : col2[c]*scal2;
        }
        v2c[j] = v2v;
      }
      for (int r = lo + wave; r < 512; r += 4){
        double* Ar = &At[(r-TBASE)*128];
        double vr = vv[r], wr = wv[r];
        double p = 0.0;
        #pragma unroll
        for (int j=0;j<8;j++){
          int c = lo + lane + 64*j;
          if (c < 512){
            double an = Ar[c-TBASE] - vr*wvc[j] - wr*vvc[j];
            Ar[c-TBASE] = an;
            p += an * v2c[j];
            if (c == lo2) colN[r] = an;
          }
        }
        #pragma unroll
        for (int off=32; off; off>>=1) p += __shfl_down(p, off, 64);
        if (lane==0) accN[r] = p;
      }
    }
    __syncthreads();                                   // S4
    for (int r=t; r<512; r+=256){
      if (r >= lo2){
        double v = (r==lo2) ? 1.0 : ((tau2==0.0) ? 0.0 : col2[r]*scal2);
        vv[r]=v;
        V[(size_t)lo*512 + r] = v;
        col2[r] = colN[r];
        acc[r] = accN[r];
      }
    }
    tauv = tau2;
    __syncthreads();                                   // S5
  }
  for (int rl=t; rl<TSZ; rl+=256) d[TBASE+rl] = At[rl*128+rl];
}

// sstedc-style pre-scale + tear
__global__ void k_scale(double* smalls, int sbase){
  int sg = sbase + blockIdx.x, t = threadIdx.x;
  double* d = smalls + (size_t)sg*512;
  double* e = smalls + 4096 + (size_t)sg*512;
  __shared__ double red[256];
  double m = 0.0;
  for (int i=t;i<512;i+=256) m = fmax(m, fabs(d[i]));
  for (int i=t;i<511;i+=256) m = fmax(m, fabs(e[i]));
  red[t]=m; __syncthreads();
  for (int off=128; off; off>>=1){ if (t<off) red[t]=fmax(red[t],red[t+off]); __syncthreads(); }
  double org = red[0]; if (org == 0.0) org = 1.0;
  if (t==0) smalls[12288+sg] = org;
  double inv = 1.0/org;
  __syncthreads();
  for (int i=t;i<512;i+=256) d[i] *= inv;
  for (int i=t;i<511;i+=256) e[i] *= inv;
  __syncthreads();
  if (t < 31){
    int k = t + 1;
    double ae = fabs(e[16*k - 1]);
    d[16*k - 1] -= ae;
    d[16*k]     -= ae;
  }
}

// 32 leaves of 16 per matrix; ONE WAVE per leaf (4 leaves / 256-thread block).
__global__ __launch_bounds__(256) void k_leaves(double* smalls, double* Zb, int sbase){
  __shared__ double LA[4][256];
  __shared__ double LQ[4][256];
  int t = threadIdx.x, w = t >> 6, lane = t & 63;
  int L = blockIdx.x*4 + w;          // leaf id
  int s_local = L >> 5;
  int sg = sbase + s_local;
  int leaf = L & 31;
  double* dd = smalls + (size_t)sg*512;
  double* ee = smalls + 4096 + (size_t)sg*512;
  double* Z = Zb + (size_t)s_local*MATSZ;
  int base = leaf*16;
  double* A = LA[w]; double* Q = LQ[w];

  for (int i=lane; i<256; i+=64){ A[i]=0.0; Q[i]=0.0; }
  __builtin_amdgcn_sched_barrier(0);
  if (lane < 16){ A[lane*17] = dd[base+lane]; Q[lane*17] = 1.0; }
  if (lane < 15){
    double ev = ee[base+lane];
    A[lane*16+lane+1] = ev; A[(lane+1)*16+lane] = ev;
  }
  __builtin_amdgcn_sched_barrier(0);
  double nr = 0.0;
  if (lane == 0){ for (int i=0;i<256;i++) nr += A[i]*A[i]; }
  nr = __shfl(nr, 0, 64);
  double thr = nr*1e-30 + 1e-300;

  for (int sweep=0; sweep<60; sweep++){
    double offs = 0.0;
    for (int p=0;p<15;p++) for (int q=p+1;q<16;q++){
      double apq = A[p*16+q];
      offs += 2.0*apq*apq;
      if (apq == 0.0) continue;
      double theta = 0.5*(A[q*17]-A[p*17])/apq;
      double tt;
      if (fabs(theta) > 1e18) tt = 0.5/theta;
      else tt = copysign(1.0, theta)/(fabs(theta)+sqrt(theta*theta+1.0));
      double cc = 1.0/sqrt(tt*tt+1.0), ss = tt*cc;
      __builtin_amdgcn_sched_barrier(0);
      if (lane < 16){
        int k = lane;
        double akp=A[k*16+p], akq=A[k*16+q];
        A[k*16+p] = cc*akp - ss*akq;
        A[k*16+q] = ss*akp + cc*akq;
      }
      __builtin_amdgcn_sched_barrier(0);
      if (lane < 16){
        int k = lane;
        double apk=A[p*16+k], aqk=A[q*16+k];
        A[p*16+k] = cc*apk - ss*aqk;
        A[q*16+k] = ss*apk + cc*aqk;
      }
      __builtin_amdgcn_sched_barrier(0);
      if (lane < 16){
        int k = lane;
        double qkp=Q[k*16+p], qkq=Q[k*16+q];
        Q[k*16+p] = cc*qkp - ss*qkq;
        Q[k*16+q] = ss*qkp + cc*qkq;
      }
      __builtin_amdgcn_sched_barrier(0);
    }
    if (offs < thr) break;
  }
  __builtin_amdgcn_sched_barrier(0);
  if (lane == 0){
    for (int i=0;i<16;i++){
      int mi=i;
      for (int j=i+1;j<16;j++) if (A[j*17] < A[mi*17]) mi=j;
      if (mi!=i){
        double tmp=A[i*17]; A[i*17]=A[mi*17]; A[mi*17]=tmp;
        for (int k=0;k<16;k++){ double q1=Q[k*16+i]; Q[k*16+i]=Q[k*16+mi]; Q[k*16+mi]=q1; }
      }
    }
  }
  __builtin_amdgcn_sched_barrier(0);
  if (lane < 16) dd[base+lane] = A[lane*17];
  for (int i=lane; i<256; i+=64){
    int r = i >> 4, c = i & 15;
    Z[(size_t)(base+r)*512 + base + c] = Q[i];
  }
}

// ---- secular solve --------------------------------------------------------
__global__ __launch_bounds__(256) void k_deflate(double* smalls, const double* Zsrc_b,
                                                 double* bscr, int level, int sbase){
  const double EPS32 = 5.9604644775390625e-8;
  const double ISQ2  = 0.70710678118654752440;
  int s_local = blockIdx.x;
  int sg = sbase + s_local;
  int hh = 16 << level, n = hh << 1;
  int merge = blockIdx.y, start = merge*n;
  double* d = smalls + (size_t)sg*512;
  const double* e = smalls + 4096 + (size_t)sg*512;
  const double* Z = Zsrc_b + (size_t)s_local*MATSZ;
  double* rotg = smalls + 12544 + (size_t)(sg*32+merge)*1024;
  double* dkG  = bscr + BD_DK  + (size_t)s_local*512 + start;
  double* zkG  = bscr + BD_ZK  + (size_t)s_local*512 + start;
  double* rzkG = bscr + BD_RZK + (size_t)s_local*512 + start;
  double* dsG  = bscr + BD_DS  + (size_t)s_local*512 + start;
  double* rhoG = bscr + BD_RHO;
  int* kidxG = (int*)(bscr + BD_KIDX) + s_local*512 + start;
  int* didxG = (int*)(bscr + BD_DIDX) + s_local*512 + start;
  int* permG = (int*)(bscr + BD_PERM) + s_local*512 + start;
  int* cntG  = (int*)(bscr + BD_CNT) + (s_local*32+merge)*2;

  __shared__ double ds[512], zl[512];
  __shared__ double rc[256], rs[256];
  __shared__ double red[256];
  __shared__ double sv[2];
  __shared__ int perm[512], kidx[512], didx[512];
  __shared__ int rp[256], rq[256];
  __shared__ int counts[2];
  int t = threadIdx.x;
  if (t == 0){
    int i=0, j=hh, k=0;
    while (i < hh && j < n){
      if (d[start+i] <= d[start+j]) perm[k++]=i++; else perm[k++]=j++;
    }
    while (i < hh) perm[k++]=i++;
    while (j < n)  perm[k++]=j++;
  }
  __syncthreads();
  double eb = e[start+hh-1];
  double rho = 2.0*fabs(eb);
  double sgn = (eb < 0.0) ? -1.0 : 1.0;
  for (int i=t; i<n; i+=NT){
    int p = perm[i];
    ds[i] = d[start+p];
    double zr = (p < hh) ? Z[(size_t)(start+hh-1)*512 + start + p]
                         : sgn * Z[(size_t)(start+hh)*512 + start + p];
    zl[i] = zr * ISQ2;
  }
  __syncthreads();
  double m = 0.0;
  for (int i=t;i<n;i+=NT) m = fmax(m, fabs(zl[i]));
  red[t]=m; __syncthreads();
  for (int off=128; off; off>>=1){ if (t<off) red[t]=fmax(red[t],red[t+off]); __syncthreads(); }
  if (t==0) sv[0] = red[0];
  __syncthreads();
  m = 0.0;
  for (int i=t;i<n;i+=NT) m = fmax(m, fabs(ds[i]));
  red[t]=m; __syncthreads();
  for (int off=128; off; off>>=1){ if (t<off) red[t]=fmax(red[t],red[t+off]); __syncthreads(); }
  if (t==0) sv[1] = red[0];
  __syncthreads();
  double zmaxv = sv[0];
  double tol = 8.0*EPS32*fmax(sv[1], zmaxv);

  if (t == 0){
    int K=0, nd=0, nrot=0;
    if (rho*zmaxv <= tol){
      for (int j=0;j<n;j++) didx[nd++]=j;
    } else {
      int pj = -1;
      for (int j=0;j<n;j++){
        if (rho*fabs(zl[j]) <= tol){
          didx[nd++]=j;
        } else if (pj < 0){
          pj = j;
        } else {
          double s_ = zl[pj], c_ = zl[j];
          double tau2 = sqrt(c_*c_ + s_*s_);
          double tdf = ds[j] - ds[pj];
          double cc = c_/tau2, sr = -s_/tau2;
          if (fabs(tdf*cc*sr) <= tol){
            zl[j] = tau2; zl[pj] = 0.0;
            if (nrot < 256){
              rp[nrot]=perm[pj]; rq[nrot]=perm[j]; rc[nrot]=cc; rs[nrot]=sr; nrot++;
            }
            double tn = ds[pj]*cc*cc + ds[j]*sr*sr;
            ds[j]  = ds[pj]*sr*sr + ds[j]*cc*cc;
            ds[pj] = tn;
            didx[nd++] = pj;
            pj = j;
          } else {
            kidx[K++] = pj;
            pj = j;
          }
        }
      }
      if (pj >= 0) kidx[K++] = pj;
    }
    for (int a=1;a<nd;a++){
      int v = didx[a]; double dv = ds[v]; int b = a-1;
      while (b >= 0 && ds[didx[b]] > dv){ didx[b+1]=didx[b]; b--; }
      didx[b+1] = v;
    }
    counts[0]=K; counts[1]=nd;
    cntG[0]=K; cntG[1]=nd;
    rhoG[s_local*32+merge] = rho;
    rotg[0] = (double)nrot;
    for (int i=0;i<nrot;i++){
      rotg[1+4*i]=(double)rp[i]; rotg[2+4*i]=(double)rq[i];
      rotg[3+4*i]=rc[i]; rotg[4+4*i]=rs[i];
    }
  }
  __syncthreads();
  int K = counts[0], nd = counts[1];
  for (int k=t; k<K; k+=NT){
    int ki = kidx[k];
    double dv = ds[ki], zv = zl[ki];
    dkG[k]=dv; zkG[k]=zv; rzkG[k]=(rho*zv)*zv; kidxG[k]=ki;
  }
  for (int j=t; j<n;  j+=NT){ dsG[j]=ds[j]; permG[j]=perm[j]; }
  for (int j=t; j<nd; j+=NT) didxG[j]=didx[j];
}

// k_bisect: one WAVE per secular root.
__global__ __launch_bounds__(256) void k_bisect(double* bscr, int level, int split){
  int s_local = blockIdx.x;
  int hh = 16 << level, n = hh << 1;
  int merge = blockIdx.y, start = merge*n;
  const double* dkG  = bscr + BD_DK  + (size_t)s_local*512 + start;
  const double* zkG  = bscr + BD_ZK  + (size_t)s_local*512 + start;
  const double* rzkG = bscr + BD_RZK + (size_t)s_local*512 + start;
  double* taukG = bscr + BD_TAU + (size_t)s_local*512 + start;
  int* KskG = (int*)(bscr + BD_KSK) + s_local*512 + start;
  const int* cntG = (int*)(bscr + BD_CNT) + (s_local*32+merge)*2;
  double rho = (bscr + BD_RHO)[s_local*32+merge];
  __shared__ double dks[512], rzks[512], zks[512];
  int t = threadIdx.x;
  int K = cntG[0];
  for (int i=t;i<K;i+=NT){ dks[i]=dkG[i]; rzks[i]=rzkG[i]; zks[i]=zkG[i]; }
  __syncthreads();
  int lane = t & 63, w = t >> 6;
  for (int j2 = blockIdx.z*4 + w; j2 < K; j2 += split*4){
    int Kb; double lo, hi;
    if (j2 < K-1){
      double mid = 0.5*(dks[j2+1]-dks[j2]);
      double dj = dks[j2];
      double part = 0.0;
      for (int i=lane;i<K;i+=64){ double dif=(dks[i]-dj)-mid; part += rzks[i]/dif; }
      #pragma unroll
      for (int off=32; off; off>>=1) part += __shfl_xor(part, off, 64);
      double gg = 1.0 + part;
      if (gg >= 0.0){ Kb=j2;   lo=0.0;  hi=mid; }
      else          { Kb=j2+1; lo=-mid; hi=0.0; }
    } else {
      double part = 0.0;
      for (int i=lane;i<K;i+=64) part += zks[i]*zks[i];
      #pragma unroll
      for (int off=32; off; off>>=1) part += __shfl_xor(part, off, 64);
      Kb=K-1; lo=0.0; hi=rho*part + 1e-300;
    }
    double dK = dks[Kb];
    for (int it=0; it<72; it++){
      double mid = 0.5*(lo+hi);
      if (mid==lo || mid==hi) break;
      double part = 0.0;
      for (int i=lane;i<K;i+=64){ double dif=(dks[i]-dK)-mid; part += rzks[i]/dif; }
      #pragma unroll
      for (int off=32; off; off>>=1) part += __shfl_xor(part, off, 64);
      double gg = 1.0 + part;
      if (gg < 0.0) lo=mid; else hi=mid;
    }
    if (lane==0){ KskG[j2]=Kb; taukG[j2]=0.5*(lo+hi); }
  }
}

// k_sfin: Gu-Eisenstat z-hat, merge ordering, S-column assembly, + fused rot.
__global__ __launch_bounds__(256) void k_sfin(double* smalls, double* Sm_b,
                                              const double* bscr, int level, int sbase){
  int s_local = blockIdx.x;
  int sg = sbase + s_local;
  int hh = 16 << level, n = hh << 1;
  int merge = blockIdx.y, start = merge*n;
  double* d = smalls + (size_t)sg*512;
  double* Sm = Sm_b + (size_t)s_local*MATSZ;
  const double* rotg = smalls + 12544 + (size_t)(sg*32+merge)*1024;
  const double* dkG  = bscr + BD_DK  + (size_t)s_local*512 + start;
  const double* zkG  = bscr + BD_ZK  + (size_t)s_local*512 + start;
  const double* taukG= bscr + BD_TAU + (size_t)s_local*512 + start;
  const double* dsG  = bscr + BD_DS  + (size_t)s_local*512 + start;
  const int* KskG = (int*)(bscr + BD_KSK) + s_local*512 + start;
  const int* kidxG= (int*)(bscr + BD_KIDX) + s_local*512 + start;
  const int* didxG= (int*)(bscr + BD_DIDX) + s_local*512 + start;
  const int* permG= (int*)(bscr + BD_PERM) + s_local*512 + start;
  const int* cntG = (int*)(bscr + BD_CNT) + (s_local*32+merge)*2;
  double rho = (bscr + BD_RHO)[s_local*32+merge];
  __shared__ double dk[512], zk[512], tauk[512], zh[512], outlam[512], ds[512];
  __shared__ int Ksk[512], kidx[512], didx[512], perm[512], outid[512];
  int t = threadIdx.x;
  int K = cntG[0], nd = cntG[1];
  for (int i=t;i<K;i+=NT){
    dk[i]=dkG[i]; zk[i]=zkG[i]; tauk[i]=taukG[i]; Ksk[i]=KskG[i]; kidx[i]=kidxG[i];
  }
  for (int i=t;i<n;i+=NT){ ds[i]=dsG[i]; perm[i]=permG[i]; }
  for (int i=t;i<nd;i+=NT) didx[i]=didxG[i];
  __syncthreads();
  for (int i=t; i<K; i+=NT){
    double P = (Ksk[i]==i) ? tauk[i] : (dk[Ksk[i]]-dk[i]) + tauk[i];
    for (int j=0;j<K;j++){
      if (j==i) continue;
      double num = (dk[Ksk[j]]-dk[i]) + tauk[j];
      double den = dk[j]-dk[i];
      P *= num/den;
    }
    zh[i] = copysign(sqrt(fabs(P/rho)), zk[i]);
  }
  __syncthreads();
  if (t == 0){
    int a=0, b=0;
    for (int j=0;j<n;j++){
      double la = (a<K)  ? (dk[Ksk[a]]+tauk[a]) : 1e300;
      double lb = (b<nd) ? ds[didx[b]]          : 1e300;
      if (la <= lb){ outid[j]=a;     outlam[j]=la; a++; }
      else         { outid[j]=512+b; outlam[j]=lb; b++; }
    }
  }
  __syncthreads();
  for (int j=t; j<n; j+=NT) d[start+j] = outlam[j];
  int cnt = (int)rotg[0];
  for (int j=t; j<n; j+=NT){
    double* col = Sm + (size_t)(start+j)*512;
    int id = outid[j];
    for (int i=0;i<n;i++) col[i]=0.0;
    if (id >= 512){
      col[perm[didx[id-512]]] = 1.0;
    } else {
      int k = id;
      double ss_ = 0.0;
      for (int i=0;i<K;i++){
        double dif = (dk[i]-dk[Ksk[k]]) - tauk[k];
        if (dif == 0.0) dif = 1e-300;
        double v = zh[i]/dif;
        col[perm[kidx[i]]] = v; ss_ += v*v;
      }
      double inv = 1.0/sqrt(ss_);
      for (int i=0;i<K;i++) col[perm[kidx[i]]] *= inv;
    }
    for (int i=cnt-1; i>=0; i--){
      int p = (int)rotg[1+4*i], q = (int)rotg[2+4*i];
      double c = rotg[3+4*i], sr = rotg[4+4*i];
      double a = col[p], b = col[q];
      col[p] = c*a - sr*b;
      col[q] = sr*a + c*b;
    }
  }
}

// Zdst[merge square] = Zsrc[:,local-cols] * S
__global__ __launch_bounds__(256) void k_gemm64(const double* Zsrc_b, const double* Sm_b,
                                                double* Zdst_b, int level){
  int hh = 16 << level, n = hh << 1;
  int mpm = 512 / n;
  int bz = blockIdx.z;
  int s = bz / mpm, merge = bz % mpm;
  int start = merge*n;
  const double* Zs = Zsrc_b + (size_t)s*MATSZ;
  const double* Sm = Sm_b + (size_t)s*MATSZ;
  double* Zd = Zdst_b + (size_t)s*MATSZ;
  int row0 = start + blockIdx.y*32, col0 = start + blockIdx.x*32;
  int t = threadIdx.x;
  int tr = t >> 4, tc = t & 15;
  __shared__ double As[32][33];
  __shared__ double Bs[32][33];
  double a00=0,a01=0,a10=0,a11=0;
  for (int q0=0; q0<n; q0+=32){
    #pragma unroll
    for (int it=0; it<4; it++){
      int idx = t + it*256;
      int r = idx >> 5, q = idx & 31;
      As[r][q] = Zs[(size_t)(row0+r)*512 + start + q0 + q];
    }
    #pragma unroll
    for (int it=0; it<4; it++){
      int idx = t + it*256;
      int c = idx >> 5, q = idx & 31;
      Bs[q][c] = Sm[(size_t)(col0+c)*512 + q0 + q];
    }
    __syncthreads();
    #pragma unroll 8
    for (int q=0;q<32;q++){
      double ar0=As[tr][q], ar1=As[tr+16][q];
      double bc0=Bs[q][tc], bc1=Bs[q][tc+16];
      a00 = fma(ar0,bc0,a00); a01 = fma(ar0,bc1,a01);
      a10 = fma(ar1,bc0,a10); a11 = fma(ar1,bc1,a11);
    }
    __syncthreads();
  }
  Zd[(size_t)(row0+tr)*512 + col0+tc]       = a00;
  Zd[(size_t)(row0+tr)*512 + col0+tc+16]    = a01;
  Zd[(size_t)(row0+tr+16)*512 + col0+tc]    = a10;
  Zd[(size_t)(row0+tr+16)*512 + col0+tc+16] = a11;
}

// apply Q = H(1)...H(n-1) to Z from the left (reverse reflector order)
__global__ __launch_bounds__(256) void k_backq(double* Z2_b, const double* Vh_b,
                                               const double* smalls, int sbase){
  int s_local = blockIdx.x, cb = blockIdx.y;
  int sg = sbase + s_local;
  double* Z = Z2_b + (size_t)s_local*MATSZ;
  const double* V = Vh_b + (size_t)sg*MATSZ;
  const double* tu = smalls + 8192 + (size_t)sg*512;
  int cg = threadIdx.x >> 5, lane = threadIdx.x & 31;
  int c = cb*8 + cg;
  __shared__ double zc[8][512];
  for (int r=lane; r<512; r+=32) zc[cg][r] = Z[(size_t)r*512 + c];
  for (int i=509; i>=0; i--){
    double tv = tu[i];
    if (tv == 0.0) continue;
    double wp = 0.0;
    for (int r=i+1+lane; r<512; r+=32) wp += V[(size_t)i*512 + r]*zc[cg][r];
    #pragma unroll
    for (int off=16; off; off>>=1) wp += __shfl_down(wp, off, 32);
    double w = __shfl(wp, 0, 32);
    double tw = tv*w;
    for (int r=i+1+lane; r<512; r+=32) zc[cg][r] -= tw*V[(size_t)i*512 + r];
  }
  for (int r=lane; r<512; r+=32) Z[(size_t)r*512 + c] = zc[cg][r];
}

// coalesced transpose finalize: 32x32 LDS tiles (bit-identical values)
__global__ void k_finalize(const double* Z2_b, const double* smalls,
                           float* Vs32, float* Vt32, float* eig, int sbase){
  int s_local = blockIdx.x;
  int sg = sbase + s_local;
  const double* Z = Z2_b + (size_t)s_local*MATSZ;
  float* Vt_pass = (sg < 4) ? (Vs32 + (size_t)sg*MATSZ)
                            : (Vt32 + (size_t)(sg-4)*MATSZ);
  int t = threadIdx.x;
  int tr = blockIdx.y & 15, tc = blockIdx.y >> 4;
  __shared__ float ft[32][33];
  {
    int i = t >> 3, j4 = (t & 7) << 2;     // row i (0..31), 4 cols
    const double* zr = &Z[(size_t)(tr*32 + i)*512 + tc*32 + j4];
    ft[i][j4+0] = (float)zr[0];
    ft[i][j4+1] = (float)zr[1];
    ft[i][j4+2] = (float)zr[2];
    ft[i][j4+3] = (float)zr[3];
  }
  __syncthreads();
  {
    int j = t >> 3, i4 = (t & 7) << 2;     // out row j, 4 cols
    float* vr = &Vt_pass[(size_t)(tc*32 + j)*512 + tr*32 + i4];
    vr[0] = ft[i4+0][j];
    vr[1] = ft[i4+1][j];
    vr[2] = ft[i4+2][j];
    vr[3] = ft[i4+3][j];
  }
  if (blockIdx.y == 0){
    double org = smalls[12288+sg];
    for (int idx=t; idx<512; idx+=256)
      eig[(size_t)sg*512 + idx] = (float)(smalls[(size_t)sg*512 + idx]*org);
  }
}

// --------------------------- diffusion (f32) --------------------------------
struct StepP { float t, a, bc; unsigned k0, k1, k2, k3; unsigned pad; };

struct KDiff {
  const float *Vt, *Vt2;
  float *xspec, *hbuf, *x, *E;
  const float *W1s, *W1t, *W2s, *W2t;
  const float *b2s, *b2t, *wts, *wtt;
  const StepP* steps;
  int nsteps;
};

// One 64x32 tile of one diffusion phase — byte-for-byte the same math as the
// proven split k_gemm32 (nmat=8, ntx=8 mapping). Called with runtime `mode`
// so a single body is emitted.
__device__ void diff_tile(const KDiff& D, int mode,
                          float st, float sa, float sbc,
                          unsigned nk0, unsigned nk1, unsigned nk2, unsigned nk3){
  int t = threadIdx.x;
  int L = blockIdx.x;
  int mat = L % 8;
  int tile = L / 8;
  int n0 = (tile % 8) << 5;
  int m0 = (tile / 8) << 6;
  const float *A, *B; float *C;
  int lda, K, chain = mat >> 2;
  if (mode == 0){
    A = (mat < 4) ? (D.Vt + (size_t)mat*MATSZ) : (D.Vt2 + (size_t)(mat-4)*MATSZ);
    lda = 512; K = 512;
    B = D.x + (size_t)mat*SZF; C = D.xspec + (size_t)mat*SZF;
  } else if (mode == 1){
    A = D.xspec + (size_t)mat*SZF; lda = 256; K = 256;
    B = chain ? D.W1t : D.W1s; C = D.hbuf + (size_t)mat*SZF;
  } else {
    A = D.hbuf + (size_t)mat*SZF; lda = 256; K = 256;
    B = chain ? D.W2t : D.W2s; C = D.x + (size_t)mat*SZF;
  }
  __shared__ float As[2][32][68];
  __shared__ float Bs[2][32][36];
  float acc[4][2] = {{0}};
  const int ra = t >> 2, kk4 = (t & 3) << 2;
  const int kb = (t & 127) >> 3, c4 = (t & 7) << 2;
  const int tr4 = (t >> 4) << 2, tc2 = (t & 15) << 1;
  const float* Aptr = &A[(size_t)(m0 + ra)*lda + kk4];
  const float* Bptr = &B[(size_t)kb*256 + n0 + c4];
  {
    const float4 av  = *(const float4*)Aptr;
    const float4 av2 = *(const float4*)(Aptr + 16);
    As[0][kk4+0][ra]=av.x;  As[0][kk4+1][ra]=av.y;  As[0][kk4+2][ra]=av.z;  As[0][kk4+3][ra]=av.w;
    As[0][16+kk4+0][ra]=av2.x; As[0][16+kk4+1][ra]=av2.y; As[0][16+kk4+2][ra]=av2.z; As[0][16+kk4+3][ra]=av2.w;
    if (t < 128){
      const float4 bv  = *(const float4*)Bptr;
      const float4 bv2 = *(const float4*)(Bptr + (size_t)16*256);
      *(float4*)&Bs[0][kb][c4] = bv;
      *(float4*)&Bs[0][kb+16][c4] = bv2;
    }
  }
  int buf = 0;
  for (int k0=0; k0<K; k0+=32){
    __syncthreads();
    bool more = (k0+32) < K;
    float4 avN, avN2, bvN, bvN2;
    if (more){
      avN  = *(const float4*)(Aptr + k0 + 32);
      avN2 = *(const float4*)(Aptr + k0 + 48);
      if (t < 128){
        bvN  = *(const float4*)(Bptr + (size_t)(k0+32)*256);
        bvN2 = *(const float4*)(Bptr + (size_t)(k0+48)*256);
      }
    }
    {
      const float (*Asb)[68] = As[buf];
      const float (*Bsb)[36] = Bs[buf];
      #pragma unroll
      for (int kk=0; kk<32; kk++){
        const float4 a4 = *(const float4*)&Asb[kk][tr4];
        const float2 b2 = *(const float2*)&Bsb[kk][tc2];
        const float ar[4] = {a4.x, a4.y, a4.z, a4.w};
        #pragma unroll
        for (int q=0;q<4;q++){
          acc[q][0] = fmaf(ar[q], b2.x, acc[q][0]);
          acc[q][1] = fmaf(ar[q], b2.y, acc[q][1]);
        }
      }
    }
    if (more){
      int nb = buf^1;
      As[nb][kk4+0][ra]=avN.x;  As[nb][kk4+1][ra]=avN.y;  As[nb][kk4+2][ra]=avN.z;  As[nb][kk4+3][ra]=avN.w;
      As[nb][16+kk4+0][ra]=avN2.x; As[nb][16+kk4+1][ra]=avN2.y; As[nb][16+kk4+2][ra]=avN2.z; As[nb][16+kk4+3][ra]=avN2.w;
      if (t < 128){
        *(float4*)&Bs[nb][kb][c4] = bvN;
        *(float4*)&Bs[nb][kb+16][c4] = bvN2;
      }
      buf = nb;
    }
  }
  #pragma unroll
  for (int q=0;q<4;q++){
    int r = m0 + tr4 + q;
    size_t rowoff = (size_t)r*256 + n0 + tc2;
    float2 cv;
    if (mode == 2) cv = *(const float2*)&C[rowoff];
    float res[2];
    #pragma unroll
    for (int p=0;p<2;p++){
      int c = n0 + tc2 + p;
      size_t oi = (size_t)r*256 + c;
      float v = acc[q][p];
      if (mode == 1){
        v += D.E[(size_t)mat*SZF + oi] + st * ((chain ? D.wtt : D.wts)[c]);
        float sg = 1.0f/(1.0f + expf(-v));
        v = v * sg;
      } else if (mode == 2){
        float bias = (chain ? D.b2t : D.b2s)[c];
        unsigned j = ((unsigned)(mat & 3))*131072u + (unsigned)oi;
        unsigned kk0 = chain ? nk2 : nk0;
        unsigned kk1 = chain ? nk3 : nk1;
        unsigned y0, y1;
        tf2x32(kk0, kk1, 0u, j, &y0, &y1);
        float nz = bits_to_normal(y0 ^ y1);
        float cx = (p==0) ? cv.x : cv.y;
        v = cx + sa*(v + bias) + sbc*nz;
      }
      res[p] = v;
    }
    *(float2*)&C[rowoff] = make_float2(res[0], res[1]);
  }
}

// Cooperative diffusion: 512 blocks (2/CU), grid.sync between phases.
__global__ __launch_bounds__(256) void k_diff(KDiff D){
  cg::grid_group grid = cg::this_grid();
  for (int k=0; k<D.nsteps; k++){
    StepP sp = D.steps[k];
    diff_tile(D, 0, sp.t, sp.a, sp.bc, sp.k0, sp.k1, sp.k2, sp.k3);
    grid.sync();
    diff_tile(D, 1, sp.t, sp.a, sp.bc, sp.k0, sp.k1, sp.k2, sp.k3);
    grid.sync();
    diff_tile(D, 2, sp.t, sp.a, sp.bc, sp.k0, sp.k1, sp.k2, sp.k3);
    grid.sync();
  }
}

// --------------------- split-path diffusion (fallback) ----------------------
struct KArgs {
  const float* Vt;
  const float* Vt2;
  float *xspec, *hbuf, *x, *E;
  const float *W1s, *W1t, *W2s, *W2t;
  const float *b2s, *b2t, *wts, *wtt, *b1s, *b1t, *wes, *wet;
  const float *cond, *Wcs, *Wct;
  const float *eig;
  const float *rec, *recW, *recb;
  float* out;
  float t, a, bc;
  unsigned nk0, nk1, nk2, nk3;
  int mode, nmat, ntx;
};

__global__ __launch_bounds__(256) void k_gemm32(KArgs P){
  int t = threadIdx.x;
  int L = blockIdx.x;
  int mat = L % P.nmat;
  int tile = L / P.nmat;
  int n0 = (tile % P.ntx) << 5;
  int m0 = (tile / P.ntx) << 6;
  const float *A, *B; float *C;
  int lda, K, chain = 0;
  if (P.mode == 0){
    A = (mat < 4) ? (P.Vt + (size_t)mat*MATSZ) : (P.Vt2 + (size_t)(mat-4)*MATSZ);
    lda = 512; K = 512;
    B = P.x + (size_t)mat*SZF; C = P.xspec + (size_t)mat*SZF;
  } else if (P.mode == 1){
    chain = mat >> 2;
    A = P.xspec + (size_t)mat*SZF; lda = 256; K = 256;
    B = chain ? P.W1t : P.W1s; C = P.hbuf + (size_t)mat*SZF;
  } else if (P.mode == 2){
    chain = mat >> 2;
    A = P.hbuf + (size_t)mat*SZF; lda = 256; K = 256;
    B = chain ? P.W2t : P.W2s; C = P.x + (size_t)mat*SZF;
  } else if (P.mode == 3){
    chain = mat;
    A = P.cond; lda = 256; K = 256;
    B = chain ? P.Wct : P.Wcs; C = P.E + (size_t)chain*4*SZF;
  } else {
    A = P.rec; lda = 256; K = 256;
    B = P.recW; C = P.out;
  }
  __shared__ float As[2][32][68];
  __shared__ float Bs[2][32][36];
  float acc[4][2] = {{0}};
  const int ra = t >> 2, kk4 = (t & 3) << 2;
  const int kb = (t & 127) >> 3, c4 = (t & 7) << 2;
  const int tr4 = (t >> 4) << 2, tc2 = (t & 15) << 1;
  const float* Aptr = &A[(size_t)(m0 + ra)*lda + kk4];
  const float* Bptr = &B[(size_t)kb*256 + n0 + c4];
  {
    const float4 av  = *(const float4*)Aptr;
    const float4 av2 = *(const float4*)(Aptr + 16);
    As[0][kk4+0][ra]=av.x;  As[0][kk4+1][ra]=av.y;  As[0][kk4+2][ra]=av.z;  As[0][kk4+3][ra]=av.w;
    As[0][16+kk4+0][ra]=av2.x; As[0][16+kk4+1][ra]=av2.y; As[0][16+kk4+2][ra]=av2.z; As[0][16+kk4+3][ra]=av2.w;
    if (t < 128){
      const float4 bv  = *(const float4*)Bptr;
      const float4 bv2 = *(const float4*)(Bptr + (size_t)16*256);
      *(float4*)&Bs[0][kb][c4] = bv;
      *(float4*)&Bs[0][kb+16][c4] = bv2;
    }
  }
  int buf = 0;
  for (int k0=0; k0<K; k0+=32){
    __syncthreads();
    bool more = (k0+32) < K;
    float4 avN, avN2, bvN, bvN2;
    if (more){
      avN  = *(const float4*)(Aptr + k0 + 32);
      avN2 = *(const float4*)(Aptr + k0 + 48);
      if (t < 128){
        bvN  = *(const float4*)(Bptr + (size_t)(k0+32)*256);
        bvN2 = *(const float4*)(Bptr + (size_t)(k0+48)*256);
      }
    }
    {
      const float (*Asb)[68] = As[buf];
      const float (*Bsb)[36] = Bs[buf];
      #pragma unroll
      for (int kk=0; kk<32; kk++){
        const float4 a4 = *(const float4*)&Asb[kk][tr4];
        const float2 b2 = *(const float2*)&Bsb[kk][tc2];
        const float ar[4] = {a4.x, a4.y, a4.z, a4.w};
        #pragma unroll
        for (int q=0;q<4;q++){
          acc[q][0] = fmaf(ar[q], b2.x, acc[q][0]);
          acc[q][1] = fmaf(ar[q], b2.y, acc[q][1]);
        }
      }
    }
    if (more){
      int nb = buf^1;
      As[nb][kk4+0][ra]=avN.x;  As[nb][kk4+1][ra]=avN.y;  As[nb][kk4+2][ra]=avN.z;  As[nb][kk4+3][ra]=avN.w;
      As[nb][16+kk4+0][ra]=avN2.x; As[nb][16+kk4+1][ra]=avN2.y; As[nb][16+kk4+2][ra]=avN2.z; As[nb][16+kk4+3][ra]=avN2.w;
      if (t < 128){
        *(float4*)&Bs[nb][kb][c4] = bvN;
        *(float4*)&Bs[nb][kb+16][c4] = bvN2;
      }
      buf = nb;
    }
  }
  #pragma unroll
  for (int q=0;q<4;q++){
    int r = m0 + tr4 + q;
    size_t rowoff = (size_t)r*256 + n0 + tc2;
    float2 cv;
    if (P.mode == 2) cv = *(const float2*)&C[rowoff];
    float res[2];
    #pragma unroll
    for (int p=0;p<2;p++){
      int c = n0 + tc2 + p;
      size_t oi = (size_t)r*256 + c;
      float v = acc[q][p];
      if (P.mode == 1){
        v += P.E[(size_t)mat*SZF + oi] + P.t * ((chain ? P.wtt : P.wts)[c]);
        float sg = 1.0f/(1.0f + expf(-v));
        v = v * sg;
      } else if (P.mode == 2){
        float bias = (chain ? P.b2t : P.b2s)[c];
        unsigned j = ((unsigned)(mat & 3))*131072u + (unsigned)oi;
        unsigned kk0 = chain ? P.nk2 : P.nk0;
        unsigned kk1 = chain ? P.nk3 : P.nk1;
        unsigned y0, y1;
        tf2x32(kk0, kk1, 0u, j, &y0, &y1);
        float nz = bits_to_normal(y0 ^ y1);
        float cx = (p==0) ? cv.x : cv.y;
        v = cx + P.a*(v + bias) + P.bc*nz;
      } else if (P.mode == 3){
        int bb = r >> 9, s2 = r & 511;
        v += (chain ? P.b1t : P.b1s)[c]
           + P.eig[(size_t)(chain*4 + bb)*512 + s2] * ((chain ? P.wet : P.wes)[c]);
      } else if (P.mode == 4){
        v += P.recb[c];
      }
      res[p] = v;
    }
    *(float2*)&C[rowoff] = make_float2(res[0], res[1]);
  }
}

// fused cond + xinit
__global__ void k_init(float* cond, float* x, const float* a, const float* v,
                       const float* xT){
  size_t i = (size_t)blockIdx.x*256 + threadIdx.x;
  size_t b = i >> 17, off = i & 131071;
  x[i] = xT[((b & 3) << 17) + off];
  if (i < 524288) cond[i] = 0.5f*(a[i] + v[i]);
}

// fused rec + copy
__global__ void k_recc(float* rec, const float* x, float* out,
                       const float* a, const float* v){
  size_t i = (size_t)blockIdx.x*256 + threadIdx.x;
  if (i < 524288) rec[i] = 0.5f*(x[i] + x[i + 524288]);
  out[524288 + i] = (i < 524288) ? a[i] : v[i - 524288];
}

// ------------------------------- host --------------------------------------
extern "C" void kernel_launch(void* const* d_in, const int* in_sizes, int n_in,
                              void* d_out, int out_size, void* d_ws, size_t ws_size,
                              hipStream_t stream){
  const float* f_audio   = (const float*)d_in[1];
  const float* f_visual  = (const float*)d_in[2];
  const float* g_speaker = (const float*)d_in[3];
  const float* g_temporal= (const float*)d_in[4];
  const float* x_T       = (const float*)d_in[6];
  const float* tsW1=(const float*)d_in[7],  *tswe=(const float*)d_in[8],
             * tswt=(const float*)d_in[9],  *tsb1=(const float*)d_in[10],
             * tsWc=(const float*)d_in[11], *tsW2=(const float*)d_in[12],
             * tsb2=(const float*)d_in[13];
  const float* ttW1=(const float*)d_in[14], *ttwe=(const float*)d_in[15],
             * ttwt=(const float*)d_in[16], *ttb1=(const float*)d_in[17],
             * ttWc=(const float*)d_in[18], *ttW2=(const float*)d_in[19],
             * ttb2=(const float*)d_in[20];
  const float* recW=(const float*)d_in[21], *recb=(const float*)d_in[22];
  float* out = (float*)d_out;

  const size_t MB = 1ull << 20;
  if (ws_size < 43*MB) return;
  bool wide = ws_size >= 80*MB;       // single-pass D&C over all 8 matrices

  char* ws = (char*)d_ws;
  double* Vh     = (double*)(ws + 0);
  double* Atail  = (double*)(ws + 16*MB);
  double* A64    = (double*)(ws + 16*MB);    // D&C overlay (after tail)
  double* Zb     = wide ? (double*)(ws + 48*MB) : (double*)(ws + 24*MB);
  double* Sm     = wide ? (double*)(ws + 64*MB) : (double*)(ws + 32*MB);
  double* smalls = (double*)(ws + 40*MB);
  unsigned* slots = (unsigned*)(smalls + 295168);
  float* Vt32_s  = (float*)(ws + 0);
  float* Vt32_t  = (float*)(ws + 8*MB);
  float* eig32   = (float*)(ws + 42*MB + 512*1024);
  StepP* d_steps = (StepP*)(ws + 42*MB + 560*1024);    // 3.2 KB
  double* bscr   = (double*)(ws + 42*MB + 640*1024);   // bisect scratch (~228KB)
  float* cond  = (float*)(ws + 16*MB);
  float* E     = (float*)(ws + 18*MB);
  float* xall  = (float*)(ws + 22*MB);
  float* xspec = (float*)(ws + 26*MB);
  float* hbuf  = (float*)(ws + 30*MB);

  // ---- jax.random key schedule (host, exact threefry, PARTITIONABLE) ----
  unsigned f0, f1;
  tf2x32(0u, 42u, 0u, 0u, &f0, &f1);
  unsigned s0,s1,t0,t1;
  tf2x32(f0, f1, 0u, 0u, &s0, &s1);
  tf2x32(f0, f1, 0u, 1u, &t0, &t1);
  static StepP h_steps[100];
  for (int k=0; k<100; k++){
    unsigned sk0, sk1, tk0, tk1;
    tf2x32(s0, s1, 0u, (unsigned)k, &sk0, &sk1);
    tf2x32(t0, t1, 0u, (unsigned)k, &tk0, &tk1);
    float tf = (float)(1.0 - (double)k/99.0);
    h_steps[k].t  = tf;
    h_steps[k].a  = (float)(pow(25.0, 2.0*(double)tf) * 0.01);
    h_steps[k].bc = (float)(pow(25.0, (double)tf) * 0.1);
    h_steps[k].k0 = sk0; h_steps[k].k1 = sk1;
    h_steps[k].k2 = tk0; h_steps[k].k3 = tk1;
    h_steps[k].pad = 0;
  }
  hipMemcpyAsync(d_steps, h_steps, sizeof(h_steps), hipMemcpyHostToDevice, stream);

  hipMemsetAsync(slots, 0, 16384, stream);

  // ---- eigh: persistent head (cols 0..383) + single-block tail ----
  k_sytd2_lds<<<8*NB, 256, 0, stream>>>(g_speaker, g_temporal, Vh, smalls, slots, Atail);
  k_sy_tail<<<8, 256, 0, stream>>>(Atail, Vh, smalls);

  int npass = wide ? 1 : 2;
  int nmat  = wide ? 8 : 4;
  for (int pass=0; pass<npass; pass++){
    int sbase = wide ? 0 : 4*pass;
    k_scale<<<nmat, 256, 0, stream>>>(smalls, sbase);
    hipMemsetAsync(Zb, 0, (size_t)(wide?16:8)*MB, stream);
    hipMemsetAsync(A64, 0, (size_t)(wide?16:8)*MB, stream);
    k_leaves<<<nmat*8, 256, 0, stream>>>(smalls, Zb, sbase);
    for (int level=0; level<5; level++){
      int n = 32 << level, mpm = 512/n;
      double* src = (level & 1) ? A64 : Zb;
      double* dst = (level & 1) ? Zb  : A64;
      int split = 2 << level;
      k_deflate<<<dim3(nmat, mpm), 256, 0, stream>>>(smalls, src, bscr, level, sbase);
      k_bisect<<<dim3(nmat, mpm, split), 256, 0, stream>>>(bscr, level, split);
      k_sfin<<<dim3(nmat, mpm), 256, 0, stream>>>(smalls, Sm, bscr, level, sbase);
      k_gemm64<<<dim3(n/32, n/32, nmat*mpm), 256, 0, stream>>>(src, Sm, dst, level);
    }
    k_backq<<<dim3(nmat, 64), 256, 0, stream>>>(A64, Vh, smalls, sbase);
    k_finalize<<<dim3(nmat, 256), 256, 0, stream>>>(A64, smalls,
                                                    Vt32_s, Vt32_t, eig32, sbase);
  }

  // ---- diffusion ----
  k_init<<<4096, 256, 0, stream>>>(cond, xall, f_audio, f_visual, x_T);

  KArgs P;
  P.Vt = Vt32_s; P.Vt2 = Vt32_t;
  P.xspec = xspec; P.hbuf = hbuf; P.x = xall; P.E = E;
  P.W1s = tsW1; P.W1t = ttW1; P.W2s = tsW2; P.W2t = ttW2;
  P.b2s = tsb2; P.b2t = ttb2; P.wts = tswt; P.wtt = ttwt;
  P.b1s = tsb1; P.b1t = ttb1; P.wes = tswe; P.wet = ttwe;
  P.cond = cond; P.Wcs = tsWc; P.Wct = ttWc;
  P.eig = eig32; P.rec = xspec; P.recW = recW; P.recb = recb; P.out = out;
  P.t = 0.f; P.a = 0.f; P.bc = 0.f;
  P.nk0 = 0; P.nk1 = 0; P.nk2 = 0; P.nk3 = 0;
  P.ntx = 8;

  // mode 3: E = cond @ Wc + b1 + eig*we  (M=2048 over 2 chains)
  P.mode = 3; P.nmat = 2;
  k_gemm32<<<512, 256, 0, stream>>>(P);

  // ---- 100 steps: one cooperative kernel; fallback to split launches ----
  KDiff Dk;
  Dk.Vt = Vt32_s; Dk.Vt2 = Vt32_t;
  Dk.xspec = xspec; Dk.hbuf = hbuf; Dk.x = xall; Dk.E = E;
  Dk.W1s = tsW1; Dk.W1t = ttW1; Dk.W2s = tsW2; Dk.W2t = ttW2;
  Dk.b2s = tsb2; Dk.b2t = ttb2; Dk.wts = tswt; Dk.wtt = ttwt;
  Dk.steps = d_steps; Dk.nsteps = 100;
  void* kargs[] = { (void*)&Dk };
  hipError_t cerr = hipLaunchCooperativeKernel((const void*)k_diff,
                                               dim3(512), dim3(256),
                                               kargs, 0, stream);
  if (cerr != hipSuccess){
    for (int k=0; k<100; k++){
      P.t = h_steps[k].t; P.a = h_steps[k].a; P.bc = h_steps[k].bc;
      P.nk0 = h_steps[k].k0; P.nk1 = h_steps[k].k1;
      P.nk2 = h_steps[k].k2; P.nk3 = h_steps[k].k3;
      P.nmat = 8;
      P.mode = 0;
      k_gemm32<<<512, 256, 0, stream>>>(P);
      P.mode = 1;
      k_gemm32<<<512, 256, 0, stream>>>(P);
      P.mode = 2;
      k_gemm32<<<512, 256, 0, stream>>>(P);
    }
  }

  k_recc<<<4096, 256, 0, stream>>>(xspec, xall, out, f_audio, f_visual);
  P.mode = 4; P.nmat = 1;
  k_gemm32<<<256, 256, 0, stream>>>(P);
}

// Round 10
// 14015.021 us; speedup vs baseline: 2.0362x; 2.0362x over previous
//
#include <hip/hip_runtime.h>
#include <math.h>
#include <stdint.h>

// ---------------------------------------------------------------------------
// DualSpectralDiffusion: faithful replication of the JAX reference.
//  - f64 eigh: persistent multi-block sytd2 (A in LDS, NB=16 blocks/matrix)
//    for columns 0..383 + single-block tail; D&C w/ slaed2 deflation mimicry.
//  - exact threefry2x32 / jax.random replication (PARTITIONABLE stream)
//  - diffusion: SPLIT 3-kernel pipeline — the proven-best structure.
//    (Failed alternatives, measured: full fusion r5 +3.5ms [occupancy
//    collapse]; panel fusion r7 +3.9ms [weight streaming]; cooperative
//    grid.sync r9 +14.4ms [sync cost + LDS bank conflicts].)
//    64x32 tiles, K-step 32, 512-block grids, XCD-affine matrix mapping.
// ---------------------------------------------------------------------------

#define NT 256
#define SZF 131072          // 512*256 floats per (b) tensor
#define MATSZ 262144        // 512*512
#define NB 16               // sytd2 blocks per matrix (32 rows each, in LDS)
#define ILAST 384           // persistent kernel handles i in [0,ILAST)
#define TBASE (ILAST+1)     // 385
#define TSZ (512-TBASE)     // 127

// bisect scratch layout (double offsets from bscr), 8 slots everywhere
#define BD_DK   0
#define BD_ZK   4096
#define BD_RZK  8192
#define BD_TAU  12288
#define BD_DS   16384
#define BD_RHO  20480
#define BD_KSK  20736
#define BD_KIDX 22784
#define BD_DIDX 24832
#define BD_PERM 26880
#define BD_CNT  28928

#define ALD(p)    __hip_atomic_load((p),  __ATOMIC_RELAXED, __HIP_MEMORY_SCOPE_AGENT)
#define AST(p,v)  __hip_atomic_store((p), (v), __ATOMIC_RELAXED, __HIP_MEMORY_SCOPE_AGENT)

// ----------------------------- threefry ------------------------------------
__host__ __device__ static inline unsigned rotl32(unsigned v, int r){ return (v<<r)|(v>>(32-r)); }

__host__ __device__ static inline void tf2x32(unsigned k0, unsigned k1,
                                              unsigned x0, unsigned x1,
                                              unsigned* o0, unsigned* o1){
  unsigned ks2 = k0 ^ k1 ^ 0x1BD11BDAu;
  x0 += k0; x1 += k1;
#define TF4(r0,r1,r2,r3) \
  x0 += x1; x1 = rotl32(x1,r0); x1 ^= x0; \
  x0 += x1; x1 = rotl32(x1,r1); x1 ^= x0; \
  x0 += x1; x1 = rotl32(x1,r2); x1 ^= x0; \
  x0 += x1; x1 = rotl32(x1,r3); x1 ^= x0;
  TF4(13,15,26,6)  x0 += k1;  x1 += ks2 + 1u;
  TF4(17,29,16,24) x0 += ks2; x1 += k0 + 2u;
  TF4(13,15,26,6)  x0 += k0;  x1 += k1 + 3u;
  TF4(17,29,16,24) x0 += k1;  x1 += ks2 + 4u;
  TF4(13,15,26,6)  x0 += ks2; x1 += k0 + 5u;
#undef TF4
  *o0 = x0; *o1 = x1;
}

// XLA ErfInv f32 polynomial; matches lax.erf_inv expansion.
__device__ static inline float erfinv_xla(float x){
  float w = -log1pf(-x*x);
  float p;
  if (w < 5.0f){
    w -= 2.5f;
    p = 2.81022636e-08f;
    p = fmaf(p, w, 3.43273939e-07f);
    p = fmaf(p, w, -3.5233877e-06f);
    p = fmaf(p, w, -4.39150654e-06f);
    p = fmaf(p, w, 0.00021858087f);
    p = fmaf(p, w, -0.00125372503f);
    p = fmaf(p, w, -0.00417768164f);
    p = fmaf(p, w, 0.246640727f);
    p = fmaf(p, w, 1.50140941f);
  } else {
    w = sqrtf(w) - 3.0f;
    p = -0.000200214257f;
    p = fmaf(p, w, 0.000100950558f);
    p = fmaf(p, w, 0.00134934322f);
    p = fmaf(p, w, -0.00367342844f);
    p = fmaf(p, w, 0.00573950773f);
    p = fmaf(p, w, -0.0076224613f);
    p = fmaf(p, w, 0.00943887047f);
    p = fmaf(p, w, 1.00167406f);
    p = fmaf(p, w, 2.83297682f);
  }
  return p*x;
}

__device__ static inline float bits_to_normal(unsigned bits){
  const float MINV = -0.99999994f;   // nextafter(-1,0) in f32
  float f = __uint_as_float((bits >> 9) | 0x3f800000u) - 1.0f;
  float u = fmaxf(MINV, fmaf(f, 2.0f, MINV));
  return 1.41421356237309515f * erfinv_xla(u);
}

// ------------------------------- eigh --------------------------------------
// Persistent multi-block Householder head: columns 0..ILAST-1.
// Flag semantics: flag = number of completed publishes. Publish #0 = init
// (acc0/col0); publish #(i+1) = end of iteration i's rank-2 stores. The
// consumer of iteration i waits for all flags >= i+1, BEFORE a block-wide
// syncthreads that also orders LDS reuse.
__global__ __launch_bounds__(256) void k_sytd2_lds(const float* Gs, const float* Gt,
                                                   double* Vb, double* smalls,
                                                   unsigned* slots, double* Atail){
  int sg = blockIdx.x / NB, g = blockIdx.x % NB;
  const float* G = (sg < 4) ? (Gs + (size_t)sg*MATSZ) : (Gt + (size_t)(sg-4)*MATSZ);
  double* V = Vb + (size_t)sg*MATSZ;
  double* d  = smalls + (size_t)sg*512;
  double* e  = smalls + 4096 + (size_t)sg*512;
  double* tu = smalls + 8192 + (size_t)sg*512;
  double* acc0 = smalls + 274688 + (size_t)sg*512;
  double* acc1 = acc0 + 4096;
  double* col0 = smalls + 282880 + (size_t)sg*512;
  double* col1 = col0 + 4096;
  double* vvh  = smalls + 291072 + (size_t)sg*512;
  double* At = Atail + (size_t)sg*MATSZ;
  int t = threadIdx.x, wave = t >> 6, lane = t & 63;

  __shared__ double Arows[32][512];   // owned rows r = 16*j + g
  __shared__ double vv[512], wv[512], col2[512], acc[512];
  __shared__ double red[4];
  __shared__ double bc[4];
  __shared__ int sdead;

  if (t == 0) sdead = 0;

  for (int j=0; j<32; j++){
    int r = NB*j + g;
    for (int c=t; c<512; c+=256)
      Arows[j][c] = (double)G[(size_t)r*512 + c];
  }

  // ---------- init: reflector 0 (replicated) ----------
  for (int r=t; r<512; r+=256) col2[r] = (r>=1) ? (double)G[(size_t)r*512] : 0.0;
  __syncthreads();
  {
    double part = 0.0;
    for (int r=2+t; r<512; r+=256) part += col2[r]*col2[r];
    #pragma unroll
    for (int off=32; off; off>>=1) part += __shfl_down(part, off, 64);
    if (lane==0) red[wave]=part;
    __syncthreads();
    if (t==0){
      double xsq = red[0]+red[1]+red[2]+red[3];
      double alpha = col2[1];
      double beta,tv,scal;
      if (xsq == 0.0){ beta=alpha; tv=0.0; scal=0.0; }
      else {
        beta = -copysign(sqrt(alpha*alpha + xsq), alpha);   // LAPACK slarfg
        tv = (beta - alpha)/beta;
        scal = 1.0/(alpha - beta);
      }
      if (g==0){ e[0]=beta; tu[0]=tv; }
      bc[0]=tv; bc[1]=scal;
    }
  }
  __syncthreads();
  double tauv = bc[0];
  {
    double scal = bc[1];
    for (int r=t; r<512; r+=256){
      double v = 0.0;
      if (r==1) v = 1.0;
      else if (r>1) v = (tauv==0.0) ? 0.0 : col2[r]*scal;
      vv[r]=v;
      if (r>=1 && (r & (NB-1))==g) V[r] = v;
    }
  }
  __syncthreads();
  if (g==0){
    for (int r=1+t; r<512; r+=256) AST(&col0[r], (double)G[(size_t)r*512 + 1]);
  }
  {
    int r0 = 1 + ((g - 1) & (NB-1));
    for (int r = r0 + NB*wave; r < 512; r += 4*NB){
      const double* Ar = Arows[r>>4];
      double p = 0.0;
      for (int c=lane; c<512; c+=64) p += Ar[c]*vv[c];
      #pragma unroll
      for (int off=32; off; off>>=1) p += __shfl_down(p, off, 64);
      if (lane==0) AST(&acc0[r], p);
    }
  }
  __syncthreads();                    // drain init publishes
  if (t == 0) AST(slots + (sg*NB + g)*16, 1u);   // publish #0 done

  // ---------- main loop (fused phases), i in [0, ILAST) ----------
  for (int i=0; i<ILAST; i++){
    if (t < NB && !sdead){
      unsigned* sl = slots + (sg*NB + t)*16;
      int spins = 0;
      while (ALD(sl) < (unsigned)(i+1)){
        if (++spins > (1<<24)){ sdead = 1; break; }
        if ((spins & 3) == 0) __builtin_amdgcn_s_sleep(1);
      }
    }
    __syncthreads();
    int lo=i+1, lo2=i+2;
    double* accR = (i&1) ? acc1 : acc0;
    double* colR = (i&1) ? col1 : col0;
    double* accW = (i&1) ? acc0 : acc1;
    double* colW = (i&1) ? col0 : col1;
    double part = 0.0;
    for (int r=lo+t; r<512; r+=256){
      double a_ = ALD(&accR[r]);
      double c_ = ALD(&colR[r]);
      acc[r]=a_; col2[r]=c_;
      part += (tauv*a_)*vv[r];
    }
    #pragma unroll
    for (int off=32; off; off>>=1) part += __shfl_down(part, off, 64);
    if (lane==0) red[wave]=part;
    __syncthreads();                                   // S1
    {
      double dot = red[0]+red[1]+red[2]+red[3];
      double alpha2 = -0.5*tauv*dot;
      double vlo = vv[lo];
      double wlo = fma(alpha2, vlo, tauv*acc[lo]);
      for (int r=lo+t; r<512; r+=256){
        double wr = fma(alpha2, vv[r], tauv*acc[r]);
        wv[r]=wr;
        col2[r] = col2[r] - vv[r]*wlo - wr*vlo;
      }
    }
    __syncthreads();                                   // S2
    part = 0.0;
    for (int r=lo2+1+t; r<512; r+=256) part += col2[r]*col2[r];
    #pragma unroll
    for (int off=32; off; off>>=1) part += __shfl_down(part, off, 64);
    if (lane==0) red[wave]=part;
    __syncthreads();                                   // S3
    double tau2, scal2;
    {
      double xsq = red[0]+red[1]+red[2]+red[3];
      double alpha = col2[lo2];
      double beta;
      if (xsq == 0.0){ beta=alpha; tau2=0.0; scal2=0.0; }
      else {
        beta = -copysign(sqrt(alpha*alpha + xsq), alpha);
        tau2 = (beta - alpha)/beta;
        scal2 = 1.0/(alpha - beta);
      }
      if (t==0 && g==0){ e[lo]=beta; tu[lo]=tau2; }
    }
    {
      double vvc[8], wvc[8], v2c[8];
      #pragma unroll
      for (int j=0;j<8;j++){
        int c = lo + lane + 64*j;
        bool ok = c < 512;
        vvc[j] = ok ? vv[c] : 0.0;
        wvc[j] = ok ? wv[c] : 0.0;
        double v2v = 0.0;
        if (ok){
          if (c==lo2) v2v = 1.0;
          else if (c>lo2) v2v = (tau2==0.0) ? 0.0 : col2[c]*scal2;
        }
        v2c[j] = v2v;
      }
      int r0 = lo + ((g - lo) & (NB-1));
      for (int r = r0 + NB*wave; r < 512; r += 4*NB){
        double* Ar = Arows[r>>4];
        double vr = vv[r], wr = wv[r];
        double p = 0.0;
        #pragma unroll
        for (int j=0;j<8;j++){
          int c = lo + lane + 64*j;
          if (c < 512){
            double an = Ar[c] - vr*wvc[j] - wr*vvc[j];
            Ar[c] = an;
            p += an * v2c[j];
            if (c == lo2) AST(&colW[r], an);
          }
        }
        #pragma unroll
        for (int off=32; off; off>>=1) p += __shfl_down(p, off, 64);
        if (lane==0) AST(&accW[r], p);
      }
    }
    __syncthreads();                                   // S4 (drains ASTs)
    if (t == 0) AST(slots + (sg*NB + g)*16, (unsigned)(i+2));  // early publish
    for (int r=t; r<512; r+=256){
      double v = 0.0;
      if (r==lo2) v = 1.0;
      else if (r>lo2) v = (tau2==0.0) ? 0.0 : col2[r]*scal2;
      vv[r]=v;
      if (r>=lo2 && (r & (NB-1))==g) V[(size_t)lo*512 + r] = v;
    }
    tauv = tau2;
  }

  // ---------- handoff ----------
  if (t < 32){
    int r = NB*t + g;
    if (r <= ILAST) d[r] = Arows[t][r];
  }
  for (int j=0; j<32; j++){
    int r = NB*j + g;
    if (r >= TBASE){
      for (int c=TBASE+t; c<512; c+=256)
        At[(size_t)r*512 + c] = Arows[j][c];
    }
  }
  if (g==0){
    for (int r=t; r<512; r+=256) vvh[r] = vv[r];
  }
}

// Tail: columns ILAST..509, one block per matrix, A trailing in LDS.
__global__ __launch_bounds__(256) void k_sy_tail(const double* Atail, double* Vb,
                                                 double* smalls){
  int sg = blockIdx.x;
  double* V = Vb + (size_t)sg*MATSZ;
  double* d  = smalls + (size_t)sg*512;
  double* e  = smalls + 4096 + (size_t)sg*512;
  double* tu = smalls + 8192 + (size_t)sg*512;
  const double* accG = smalls + 274688 + (size_t)sg*512;  // parity(ILAST)=even -> base
  const double* colG = smalls + 282880 + (size_t)sg*512;
  const double* vvG  = smalls + 291072 + (size_t)sg*512;
  const double* At0 = Atail + (size_t)sg*MATSZ;
  int t = threadIdx.x, wave = t >> 6, lane = t & 63;

  __shared__ double At[TSZ*128];
  __shared__ double vv[512], wv[512], col2[512], acc[512], accN[512], colN[512];
  __shared__ double red[4];

  for (int rl=0; rl<TSZ; rl++)
    for (int cl=t; cl<TSZ; cl+=256)
      At[rl*128+cl] = At0[(size_t)(TBASE+rl)*512 + TBASE+cl];
  for (int r=t; r<512; r+=256){
    if (r >= ILAST){ vv[r]=vvG[r]; acc[r]=accG[r]; col2[r]=colG[r]; }
  }
  double tauv = tu[ILAST];
  __syncthreads();

  for (int i=ILAST; i<510; i++){
    int lo=i+1, lo2=i+2;
    double part = 0.0;
    for (int r=lo+t; r<512; r+=256) part += (tauv*acc[r])*vv[r];
    #pragma unroll
    for (int off=32; off; off>>=1) part += __shfl_down(part, off, 64);
    if (lane==0) red[wave]=part;
    __syncthreads();                                   // S1
    {
      double dot = red[0]+red[1]+red[2]+red[3];
      double alpha2 = -0.5*tauv*dot;
      double vlo = vv[lo];
      double wlo = fma(alpha2, vlo, tauv*acc[lo]);
      for (int r=lo+t; r<512; r+=256){
        double wr = fma(alpha2, vv[r], tauv*acc[r]);
        wv[r]=wr;
        col2[r] = col2[r] - vv[r]*wlo - wr*vlo;
      }
    }
    __syncthreads();                                   // S2
    part = 0.0;
    for (int r=lo2+1+t; r<512; r+=256) part += col2[r]*col2[r];
    #pragma unroll
    for (int off=32; off; off>>=1) part += __shfl_down(part, off, 64);
    if (lane==0) red[wave]=part;
    __syncthreads();                                   // S3
    double tau2, scal2;
    {
      double xsq = red[0]+red[1]+red[2]+red[3];
      double alpha = col2[lo2];
      double beta;
      if (xsq == 0.0){ beta=alpha; tau2=0.0; scal2=0.0; }
      else {
        beta = -copysign(sqrt(alpha*alpha + xsq), alpha);
        tau2 = (beta - alpha)/beta;
        scal2 = 1.0/(alpha - beta);
      }
      if (t==0){ e[lo]=beta; tu[lo]=tau2; }
    }
    {
      double vvc[8], wvc[8], v2c[8];
      #pragma unroll
      for (int j=0;j<8;j++){
        int c = lo + lane + 64*j;
        bool ok = c < 512;
        vvc[j] = ok ? vv[c] : 0.0;
        wvc[j] = ok ? wv[c] : 0.0;
        double v2v = 0.0;
        if (ok){
          if (c==lo2) v2v = 1.0;
          else if (c>lo2) v2v = (tau2==0.0) ? 0.0 : col2[c]*scal2;
        }
        v2c[j] = v2v;
      }
      for (int r = lo + wave; r < 512; r += 4){
        double* Ar = &At[(r-TBASE)*128];
        double vr = vv[r], wr = wv[r];
        double p = 0.0;
        #pragma unroll
        for (int j=0;j<8;j++){
          int c = lo + lane + 64*j;
          if (c < 512){
            double an = Ar[c-TBASE] - vr*wvc[j] - wr*vvc[j];
            Ar[c-TBASE] = an;
            p += an * v2c[j];
            if (c == lo2) colN[r] = an;
          }
        }
        #pragma unroll
        for (int off=32; off; off>>=1) p += __shfl_down(p, off, 64);
        if (lane==0) accN[r] = p;
      }
    }
    __syncthreads();                                   // S4
    for (int r=t; r<512; r+=256){
      if (r >= lo2){
        double v = (r==lo2) ? 1.0 : ((tau2==0.0) ? 0.0 : col2[r]*scal2);
        vv[r]=v;
        V[(size_t)lo*512 + r] = v;
        col2[r] = colN[r];
        acc[r] = accN[r];
      }
    }
    tauv = tau2;
    __syncthreads();                                   // S5
  }
  for (int rl=t; rl<TSZ; rl+=256) d[TBASE+rl] = At[rl*128+rl];
}

// sstedc-style pre-scale + tear
__global__ void k_scale(double* smalls, int sbase){
  int sg = sbase + blockIdx.x, t = threadIdx.x;
  double* d = smalls + (size_t)sg*512;
  double* e = smalls + 4096 + (size_t)sg*512;
  __shared__ double red[256];
  double m = 0.0;
  for (int i=t;i<512;i+=256) m = fmax(m, fabs(d[i]));
  for (int i=t;i<511;i+=256) m = fmax(m, fabs(e[i]));
  red[t]=m; __syncthreads();
  for (int off=128; off; off>>=1){ if (t<off) red[t]=fmax(red[t],red[t+off]); __syncthreads(); }
  double org = red[0]; if (org == 0.0) org = 1.0;
  if (t==0) smalls[12288+sg] = org;
  double inv = 1.0/org;
  __syncthreads();
  for (int i=t;i<512;i+=256) d[i] *= inv;
  for (int i=t;i<511;i+=256) e[i] *= inv;
  __syncthreads();
  if (t < 31){
    int k = t + 1;
    double ae = fabs(e[16*k - 1]);
    d[16*k - 1] -= ae;
    d[16*k]     -= ae;
  }
}

// 32 leaves of 16 per matrix; ONE WAVE per leaf (4 leaves / 256-thread block).
__global__ __launch_bounds__(256) void k_leaves(double* smalls, double* Zb, int sbase){
  __shared__ double LA[4][256];
  __shared__ double LQ[4][256];
  int t = threadIdx.x, w = t >> 6, lane = t & 63;
  int L = blockIdx.x*4 + w;          // leaf id
  int s_local = L >> 5;
  int sg = sbase + s_local;
  int leaf = L & 31;
  double* dd = smalls + (size_t)sg*512;
  double* ee = smalls + 4096 + (size_t)sg*512;
  double* Z = Zb + (size_t)s_local*MATSZ;
  int base = leaf*16;
  double* A = LA[w]; double* Q = LQ[w];

  for (int i=lane; i<256; i+=64){ A[i]=0.0; Q[i]=0.0; }
  __builtin_amdgcn_sched_barrier(0);
  if (lane < 16){ A[lane*17] = dd[base+lane]; Q[lane*17] = 1.0; }
  if (lane < 15){
    double ev = ee[base+lane];
    A[lane*16+lane+1] = ev; A[(lane+1)*16+lane] = ev;
  }
  __builtin_amdgcn_sched_barrier(0);
  double nr = 0.0;
  if (lane == 0){ for (int i=0;i<256;i++) nr += A[i]*A[i]; }
  nr = __shfl(nr, 0, 64);
  double thr = nr*1e-30 + 1e-300;

  for (int sweep=0; sweep<60; sweep++){
    double offs = 0.0;
    for (int p=0;p<15;p++) for (int q=p+1;q<16;q++){
      double apq = A[p*16+q];
      offs += 2.0*apq*apq;
      if (apq == 0.0) continue;
      double theta = 0.5*(A[q*17]-A[p*17])/apq;
      double tt;
      if (fabs(theta) > 1e18) tt = 0.5/theta;
      else tt = copysign(1.0, theta)/(fabs(theta)+sqrt(theta*theta+1.0));
      double cc = 1.0/sqrt(tt*tt+1.0), ss = tt*cc;
      __builtin_amdgcn_sched_barrier(0);
      if (lane < 16){
        int k = lane;
        double akp=A[k*16+p], akq=A[k*16+q];
        A[k*16+p] = cc*akp - ss*akq;
        A[k*16+q] = ss*akp + cc*akq;
      }
      __builtin_amdgcn_sched_barrier(0);
      if (lane < 16){
        int k = lane;
        double apk=A[p*16+k], aqk=A[q*16+k];
        A[p*16+k] = cc*apk - ss*aqk;
        A[q*16+k] = ss*apk + cc*aqk;
      }
      __builtin_amdgcn_sched_barrier(0);
      if (lane < 16){
        int k = lane;
        double qkp=Q[k*16+p], qkq=Q[k*16+q];
        Q[k*16+p] = cc*qkp - ss*qkq;
        Q[k*16+q] = ss*qkp + cc*qkq;
      }
      __builtin_amdgcn_sched_barrier(0);
    }
    if (offs < thr) break;
  }
  __builtin_amdgcn_sched_barrier(0);
  if (lane == 0){
    for (int i=0;i<16;i++){
      int mi=i;
      for (int j=i+1;j<16;j++) if (A[j*17] < A[mi*17]) mi=j;
      if (mi!=i){
        double tmp=A[i*17]; A[i*17]=A[mi*17]; A[mi*17]=tmp;
        for (int k=0;k<16;k++){ double q1=Q[k*16+i]; Q[k*16+i]=Q[k*16+mi]; Q[k*16+mi]=q1; }
      }
    }
  }
  __builtin_amdgcn_sched_barrier(0);
  if (lane < 16) dd[base+lane] = A[lane*17];
  for (int i=lane; i<256; i+=64){
    int r = i >> 4, c = i & 15;
    Z[(size_t)(base+r)*512 + base + c] = Q[i];
  }
}

// ---- secular solve --------------------------------------------------------
__global__ __launch_bounds__(256) void k_deflate(double* smalls, const double* Zsrc_b,
                                                 double* bscr, int level, int sbase){
  const double EPS32 = 5.9604644775390625e-8;
  const double ISQ2  = 0.70710678118654752440;
  int s_local = blockIdx.x;
  int sg = sbase + s_local;
  int hh = 16 << level, n = hh << 1;
  int merge = blockIdx.y, start = merge*n;
  double* d = smalls + (size_t)sg*512;
  const double* e = smalls + 4096 + (size_t)sg*512;
  const double* Z = Zsrc_b + (size_t)s_local*MATSZ;
  double* rotg = smalls + 12544 + (size_t)(sg*32+merge)*1024;
  double* dkG  = bscr + BD_DK  + (size_t)s_local*512 + start;
  double* zkG  = bscr + BD_ZK  + (size_t)s_local*512 + start;
  double* rzkG = bscr + BD_RZK + (size_t)s_local*512 + start;
  double* dsG  = bscr + BD_DS  + (size_t)s_local*512 + start;
  double* rhoG = bscr + BD_RHO;
  int* kidxG = (int*)(bscr + BD_KIDX) + s_local*512 + start;
  int* didxG = (int*)(bscr + BD_DIDX) + s_local*512 + start;
  int* permG = (int*)(bscr + BD_PERM) + s_local*512 + start;
  int* cntG  = (int*)(bscr + BD_CNT) + (s_local*32+merge)*2;

  __shared__ double ds[512], zl[512];
  __shared__ double rc[256], rs[256];
  __shared__ double red[256];
  __shared__ double sv[2];
  __shared__ int perm[512], kidx[512], didx[512];
  __shared__ int rp[256], rq[256];
  __shared__ int counts[2];
  int t = threadIdx.x;
  if (t == 0){
    int i=0, j=hh, k=0;
    while (i < hh && j < n){
      if (d[start+i] <= d[start+j]) perm[k++]=i++; else perm[k++]=j++;
    }
    while (i < hh) perm[k++]=i++;
    while (j < n)  perm[k++]=j++;
  }
  __syncthreads();
  double eb = e[start+hh-1];
  double rho = 2.0*fabs(eb);
  double sgn = (eb < 0.0) ? -1.0 : 1.0;
  for (int i=t; i<n; i+=NT){
    int p = perm[i];
    ds[i] = d[start+p];
    double zr = (p < hh) ? Z[(size_t)(start+hh-1)*512 + start + p]
                         : sgn * Z[(size_t)(start+hh)*512 + start + p];
    zl[i] = zr * ISQ2;
  }
  __syncthreads();
  double m = 0.0;
  for (int i=t;i<n;i+=NT) m = fmax(m, fabs(zl[i]));
  red[t]=m; __syncthreads();
  for (int off=128; off; off>>=1){ if (t<off) red[t]=fmax(red[t],red[t+off]); __syncthreads(); }
  if (t==0) sv[0] = red[0];
  __syncthreads();
  m = 0.0;
  for (int i=t;i<n;i+=NT) m = fmax(m, fabs(ds[i]));
  red[t]=m; __syncthreads();
  for (int off=128; off; off>>=1){ if (t<off) red[t]=fmax(red[t],red[t+off]); __syncthreads(); }
  if (t==0) sv[1] = red[0];
  __syncthreads();
  double zmaxv = sv[0];
  double tol = 8.0*EPS32*fmax(sv[1], zmaxv);

  if (t == 0){
    int K=0, nd=0, nrot=0;
    if (rho*zmaxv <= tol){
      for (int j=0;j<n;j++) didx[nd++]=j;
    } else {
      int pj = -1;
      for (int j=0;j<n;j++){
        if (rho*fabs(zl[j]) <= tol){
          didx[nd++]=j;
        } else if (pj < 0){
          pj = j;
        } else {
          double s_ = zl[pj], c_ = zl[j];
          double tau2 = sqrt(c_*c_ + s_*s_);
          double tdf = ds[j] - ds[pj];
          double cc = c_/tau2, sr = -s_/tau2;
          if (fabs(tdf*cc*sr) <= tol){
            zl[j] = tau2; zl[pj] = 0.0;
            if (nrot < 256){
              rp[nrot]=perm[pj]; rq[nrot]=perm[j]; rc[nrot]=cc; rs[nrot]=sr; nrot++;
            }
            double tn = ds[pj]*cc*cc + ds[j]*sr*sr;
            ds[j]  = ds[pj]*sr*sr + ds[j]*cc*cc;
            ds[pj] = tn;
            didx[nd++] = pj;
            pj = j;
          } else {
            kidx[K++] = pj;
            pj = j;
          }
        }
      }
      if (pj >= 0) kidx[K++] = pj;
    }
    for (int a=1;a<nd;a++){
      int v = didx[a]; double dv = ds[v]; int b = a-1;
      while (b >= 0 && ds[didx[b]] > dv){ didx[b+1]=didx[b]; b--; }
      didx[b+1] = v;
    }
    counts[0]=K; counts[1]=nd;
    cntG[0]=K; cntG[1]=nd;
    rhoG[s_local*32+merge] = rho;
    rotg[0] = (double)nrot;
    for (int i=0;i<nrot;i++){
      rotg[1+4*i]=(double)rp[i]; rotg[2+4*i]=(double)rq[i];
      rotg[3+4*i]=rc[i]; rotg[4+4*i]=rs[i];
    }
  }
  __syncthreads();
  int K = counts[0], nd = counts[1];
  for (int k=t; k<K; k+=NT){
    int ki = kidx[k];
    double dv = ds[ki], zv = zl[ki];
    dkG[k]=dv; zkG[k]=zv; rzkG[k]=(rho*zv)*zv; kidxG[k]=ki;
  }
  for (int j=t; j<n;  j+=NT){ dsG[j]=ds[j]; permG[j]=perm[j]; }
  for (int j=t; j<nd; j+=NT) didxG[j]=didx[j];
}

// k_bisect: one WAVE per secular root.
__global__ __launch_bounds__(256) void k_bisect(double* bscr, int level, int split){
  int s_local = blockIdx.x;
  int hh = 16 << level, n = hh << 1;
  int merge = blockIdx.y, start = merge*n;
  const double* dkG  = bscr + BD_DK  + (size_t)s_local*512 + start;
  const double* zkG  = bscr + BD_ZK  + (size_t)s_local*512 + start;
  const double* rzkG = bscr + BD_RZK + (size_t)s_local*512 + start;
  double* taukG = bscr + BD_TAU + (size_t)s_local*512 + start;
  int* KskG = (int*)(bscr + BD_KSK) + s_local*512 + start;
  const int* cntG = (int*)(bscr + BD_CNT) + (s_local*32+merge)*2;
  double rho = (bscr + BD_RHO)[s_local*32+merge];
  __shared__ double dks[512], rzks[512], zks[512];
  int t = threadIdx.x;
  int K = cntG[0];
  for (int i=t;i<K;i+=NT){ dks[i]=dkG[i]; rzks[i]=rzkG[i]; zks[i]=zkG[i]; }
  __syncthreads();
  int lane = t & 63, w = t >> 6;
  for (int j2 = blockIdx.z*4 + w; j2 < K; j2 += split*4){
    int Kb; double lo, hi;
    if (j2 < K-1){
      double mid = 0.5*(dks[j2+1]-dks[j2]);
      double dj = dks[j2];
      double part = 0.0;
      for (int i=lane;i<K;i+=64){ double dif=(dks[i]-dj)-mid; part += rzks[i]/dif; }
      #pragma unroll
      for (int off=32; off; off>>=1) part += __shfl_xor(part, off, 64);
      double gg = 1.0 + part;
      if (gg >= 0.0){ Kb=j2;   lo=0.0;  hi=mid; }
      else          { Kb=j2+1; lo=-mid; hi=0.0; }
    } else {
      double part = 0.0;
      for (int i=lane;i<K;i+=64) part += zks[i]*zks[i];
      #pragma unroll
      for (int off=32; off; off>>=1) part += __shfl_xor(part, off, 64);
      Kb=K-1; lo=0.0; hi=rho*part + 1e-300;
    }
    double dK = dks[Kb];
    for (int it=0; it<72; it++){
      double mid = 0.5*(lo+hi);
      if (mid==lo || mid==hi) break;
      double part = 0.0;
      for (int i=lane;i<K;i+=64){ double dif=(dks[i]-dK)-mid; part += rzks[i]/dif; }
      #pragma unroll
      for (int off=32; off; off>>=1) part += __shfl_xor(part, off, 64);
      double gg = 1.0 + part;
      if (gg < 0.0) lo=mid; else hi=mid;
    }
    if (lane==0){ KskG[j2]=Kb; taukG[j2]=0.5*(lo+hi); }
  }
}

// k_sfin: Gu-Eisenstat z-hat, merge ordering, S-column assembly, + fused rot.
__global__ __launch_bounds__(256) void k_sfin(double* smalls, double* Sm_b,
                                              const double* bscr, int level, int sbase){
  int s_local = blockIdx.x;
  int sg = sbase + s_local;
  int hh = 16 << level, n = hh << 1;
  int merge = blockIdx.y, start = merge*n;
  double* d = smalls + (size_t)sg*512;
  double* Sm = Sm_b + (size_t)s_local*MATSZ;
  const double* rotg = smalls + 12544 + (size_t)(sg*32+merge)*1024;
  const double* dkG  = bscr + BD_DK  + (size_t)s_local*512 + start;
  const double* zkG  = bscr + BD_ZK  + (size_t)s_local*512 + start;
  const double* taukG= bscr + BD_TAU + (size_t)s_local*512 + start;
  const double* dsG  = bscr + BD_DS  + (size_t)s_local*512 + start;
  const int* KskG = (int*)(bscr + BD_KSK) + s_local*512 + start;
  const int* kidxG= (int*)(bscr + BD_KIDX) + s_local*512 + start;
  const int* didxG= (int*)(bscr + BD_DIDX) + s_local*512 + start;
  const int* permG= (int*)(bscr + BD_PERM) + s_local*512 + start;
  const int* cntG = (int*)(bscr + BD_CNT) + (s_local*32+merge)*2;
  double rho = (bscr + BD_RHO)[s_local*32+merge];
  __shared__ double dk[512], zk[512], tauk[512], zh[512], outlam[512], ds[512];
  __shared__ int Ksk[512], kidx[512], didx[512], perm[512], outid[512];
  int t = threadIdx.x;
  int K = cntG[0], nd = cntG[1];
  for (int i=t;i<K;i+=NT){
    dk[i]=dkG[i]; zk[i]=zkG[i]; tauk[i]=taukG[i]; Ksk[i]=KskG[i]; kidx[i]=kidxG[i];
  }
  for (int i=t;i<n;i+=NT){ ds[i]=dsG[i]; perm[i]=permG[i]; }
  for (int i=t;i<nd;i+=NT) didx[i]=didxG[i];
  __syncthreads();
  for (int i=t; i<K; i+=NT){
    double P = (Ksk[i]==i) ? tauk[i] : (dk[Ksk[i]]-dk[i]) + tauk[i];
    for (int j=0;j<K;j++){
      if (j==i) continue;
      double num = (dk[Ksk[j]]-dk[i]) + tauk[j];
      double den = dk[j]-dk[i];
      P *= num/den;
    }
    zh[i] = copysign(sqrt(fabs(P/rho)), zk[i]);
  }
  __syncthreads();
  if (t == 0){
    int a=0, b=0;
    for (int j=0;j<n;j++){
      double la = (a<K)  ? (dk[Ksk[a]]+tauk[a]) : 1e300;
      double lb = (b<nd) ? ds[didx[b]]          : 1e300;
      if (la <= lb){ outid[j]=a;     outlam[j]=la; a++; }
      else         { outid[j]=512+b; outlam[j]=lb; b++; }
    }
  }
  __syncthreads();
  for (int j=t; j<n; j+=NT) d[start+j] = outlam[j];
  int cnt = (int)rotg[0];
  for (int j=t; j<n; j+=NT){
    double* col = Sm + (size_t)(start+j)*512;
    int id = outid[j];
    for (int i=0;i<n;i++) col[i]=0.0;
    if (id >= 512){
      col[perm[didx[id-512]]] = 1.0;
    } else {
      int k = id;
      double ss_ = 0.0;
      for (int i=0;i<K;i++){
        double dif = (dk[i]-dk[Ksk[k]]) - tauk[k];
        if (dif == 0.0) dif = 1e-300;
        double v = zh[i]/dif;
        col[perm[kidx[i]]] = v; ss_ += v*v;
      }
      double inv = 1.0/sqrt(ss_);
      for (int i=0;i<K;i++) col[perm[kidx[i]]] *= inv;
    }
    for (int i=cnt-1; i>=0; i--){
      int p = (int)rotg[1+4*i], q = (int)rotg[2+4*i];
      double c = rotg[3+4*i], sr = rotg[4+4*i];
      double a = col[p], b = col[q];
      col[p] = c*a - sr*b;
      col[q] = sr*a + c*b;
    }
  }
}

// Zdst[merge square] = Zsrc[:,local-cols] * S
__global__ __launch_bounds__(256) void k_gemm64(const double* Zsrc_b, const double* Sm_b,
                                                double* Zdst_b, int level){
  int hh = 16 << level, n = hh << 1;
  int mpm = 512 / n;
  int bz = blockIdx.z;
  int s = bz / mpm, merge = bz % mpm;
  int start = merge*n;
  const double* Zs = Zsrc_b + (size_t)s*MATSZ;
  const double* Sm = Sm_b + (size_t)s*MATSZ;
  double* Zd = Zdst_b + (size_t)s*MATSZ;
  int row0 = start + blockIdx.y*32, col0 = start + blockIdx.x*32;
  int t = threadIdx.x;
  int tr = t >> 4, tc = t & 15;
  __shared__ double As[32][33];
  __shared__ double Bs[32][33];
  double a00=0,a01=0,a10=0,a11=0;
  for (int q0=0; q0<n; q0+=32){
    #pragma unroll
    for (int it=0; it<4; it++){
      int idx = t + it*256;
      int r = idx >> 5, q = idx & 31;
      As[r][q] = Zs[(size_t)(row0+r)*512 + start + q0 + q];
    }
    #pragma unroll
    for (int it=0; it<4; it++){
      int idx = t + it*256;
      int c = idx >> 5, q = idx & 31;
      Bs[q][c] = Sm[(size_t)(col0+c)*512 + q0 + q];
    }
    __syncthreads();
    #pragma unroll 8
    for (int q=0;q<32;q++){
      double ar0=As[tr][q], ar1=As[tr+16][q];
      double bc0=Bs[q][tc], bc1=Bs[q][tc+16];
      a00 = fma(ar0,bc0,a00); a01 = fma(ar0,bc1,a01);
      a10 = fma(ar1,bc0,a10); a11 = fma(ar1,bc1,a11);
    }
    __syncthreads();
  }
  Zd[(size_t)(row0+tr)*512 + col0+tc]       = a00;
  Zd[(size_t)(row0+tr)*512 + col0+tc+16]    = a01;
  Zd[(size_t)(row0+tr+16)*512 + col0+tc]    = a10;
  Zd[(size_t)(row0+tr+16)*512 + col0+tc+16] = a11;
}

// apply Q = H(1)...H(n-1) to Z from the left (reverse reflector order)
__global__ __launch_bounds__(256) void k_backq(double* Z2_b, const double* Vh_b,
                                               const double* smalls, int sbase){
  int s_local = blockIdx.x, cb = blockIdx.y;
  int sg = sbase + s_local;
  double* Z = Z2_b + (size_t)s_local*MATSZ;
  const double* V = Vh_b + (size_t)sg*MATSZ;
  const double* tu = smalls + 8192 + (size_t)sg*512;
  int cg = threadIdx.x >> 5, lane = threadIdx.x & 31;
  int c = cb*8 + cg;
  __shared__ double zc[8][512];
  for (int r=lane; r<512; r+=32) zc[cg][r] = Z[(size_t)r*512 + c];
  for (int i=509; i>=0; i--){
    double tv = tu[i];
    if (tv == 0.0) continue;
    double wp = 0.0;
    for (int r=i+1+lane; r<512; r+=32) wp += V[(size_t)i*512 + r]*zc[cg][r];
    #pragma unroll
    for (int off=16; off; off>>=1) wp += __shfl_down(wp, off, 32);
    double w = __shfl(wp, 0, 32);
    double tw = tv*w;
    for (int r=i+1+lane; r<512; r+=32) zc[cg][r] -= tw*V[(size_t)i*512 + r];
  }
  for (int r=lane; r<512; r+=32) Z[(size_t)r*512 + c] = zc[cg][r];
}

// coalesced transpose finalize: 32x32 LDS tiles (bit-identical values)
__global__ void k_finalize(const double* Z2_b, const double* smalls,
                           float* Vs32, float* Vt32, float* eig, int sbase){
  int s_local = blockIdx.x;
  int sg = sbase + s_local;
  const double* Z = Z2_b + (size_t)s_local*MATSZ;
  float* Vt_pass = (sg < 4) ? (Vs32 + (size_t)sg*MATSZ)
                            : (Vt32 + (size_t)(sg-4)*MATSZ);
  int t = threadIdx.x;
  int tr = blockIdx.y & 15, tc = blockIdx.y >> 4;
  __shared__ float ft[32][33];
  {
    int i = t >> 3, j4 = (t & 7) << 2;     // row i (0..31), 4 cols
    const double* zr = &Z[(size_t)(tr*32 + i)*512 + tc*32 + j4];
    ft[i][j4+0] = (float)zr[0];
    ft[i][j4+1] = (float)zr[1];
    ft[i][j4+2] = (float)zr[2];
    ft[i][j4+3] = (float)zr[3];
  }
  __syncthreads();
  {
    int j = t >> 3, i4 = (t & 7) << 2;     // out row j, 4 cols
    float* vr = &Vt_pass[(size_t)(tc*32 + j)*512 + tr*32 + i4];
    vr[0] = ft[i4+0][j];
    vr[1] = ft[i4+1][j];
    vr[2] = ft[i4+2][j];
    vr[3] = ft[i4+3][j];
  }
  if (blockIdx.y == 0){
    double org = smalls[12288+sg];
    for (int idx=t; idx<512; idx+=256)
      eig[(size_t)sg*512 + idx] = (float)(smalls[(size_t)sg*512 + idx]*org);
  }
}

// --------------------------- diffusion (f32) --------------------------------
struct KArgs {
  const float* Vt;
  const float* Vt2;
  float *xspec, *hbuf, *x, *E;
  const float *W1s, *W1t, *W2s, *W2t;
  const float *b2s, *b2t, *wts, *wtt, *b1s, *b1t, *wes, *wet;
  const float *cond, *Wcs, *Wct;
  const float *eig;
  const float *rec, *recW, *recb;
  float* out;
  float t, a, bc;
  unsigned nk0, nk1, nk2, nk3;
  int mode, nmat, ntx;
};

// 64x32-tile GEMM, K-step 32, 512-block grids (2 blocks/CU), XCD-affine
// matrix axis. Per-element accumulation order (k ascending, single
// accumulator) identical -> bit-identical outputs.
__global__ __launch_bounds__(256) void k_gemm32(KArgs P){
  int t = threadIdx.x;
  int L = blockIdx.x;
  int mat = L % P.nmat;
  int tile = L / P.nmat;
  int n0 = (tile % P.ntx) << 5;
  int m0 = (tile / P.ntx) << 6;
  const float *A, *B; float *C;
  int lda, K, chain = 0;
  if (P.mode == 0){
    A = (mat < 4) ? (P.Vt + (size_t)mat*MATSZ) : (P.Vt2 + (size_t)(mat-4)*MATSZ);
    lda = 512; K = 512;
    B = P.x + (size_t)mat*SZF; C = P.xspec + (size_t)mat*SZF;
  } else if (P.mode == 1){
    chain = mat >> 2;
    A = P.xspec + (size_t)mat*SZF; lda = 256; K = 256;
    B = chain ? P.W1t : P.W1s; C = P.hbuf + (size_t)mat*SZF;
  } else if (P.mode == 2){
    chain = mat >> 2;
    A = P.hbuf + (size_t)mat*SZF; lda = 256; K = 256;
    B = chain ? P.W2t : P.W2s; C = P.x + (size_t)mat*SZF;
  } else if (P.mode == 3){
    chain = mat;
    A = P.cond; lda = 256; K = 256;
    B = chain ? P.Wct : P.Wcs; C = P.E + (size_t)chain*4*SZF;
  } else {
    A = P.rec; lda = 256; K = 256;
    B = P.recW; C = P.out;
  }
  __shared__ float As[2][32][68];
  __shared__ float Bs[2][32][36];
  float acc[4][2] = {{0}};
  const int ra = t >> 2, kk4 = (t & 3) << 2;          // A staging (all threads)
  const int kb = (t & 127) >> 3, c4 = (t & 7) << 2;   // B staging (t<128)
  const int tr4 = (t >> 4) << 2, tc2 = (t & 15) << 1; // compute mapping
  const float* Aptr = &A[(size_t)(m0 + ra)*lda + kk4];
  const float* Bptr = &B[(size_t)kb*256 + n0 + c4];
  {
    const float4 av  = *(const float4*)Aptr;
    const float4 av2 = *(const float4*)(Aptr + 16);
    As[0][kk4+0][ra]=av.x;  As[0][kk4+1][ra]=av.y;  As[0][kk4+2][ra]=av.z;  As[0][kk4+3][ra]=av.w;
    As[0][16+kk4+0][ra]=av2.x; As[0][16+kk4+1][ra]=av2.y; As[0][16+kk4+2][ra]=av2.z; As[0][16+kk4+3][ra]=av2.w;
    if (t < 128){
      const float4 bv  = *(const float4*)Bptr;
      const float4 bv2 = *(const float4*)(Bptr + (size_t)16*256);
      *(float4*)&Bs[0][kb][c4] = bv;
      *(float4*)&Bs[0][kb+16][c4] = bv2;
    }
  }
  int buf = 0;
  for (int k0=0; k0<K; k0+=32){
    __syncthreads();
    bool more = (k0+32) < K;
    float4 avN, avN2, bvN, bvN2;
    if (more){
      avN  = *(const float4*)(Aptr + k0 + 32);
      avN2 = *(const float4*)(Aptr + k0 + 48);
      if (t < 128){
        bvN  = *(const float4*)(Bptr + (size_t)(k0+32)*256);
        bvN2 = *(const float4*)(Bptr + (size_t)(k0+48)*256);
      }
    }
    {
      const float (*Asb)[68] = As[buf];
      const float (*Bsb)[36] = Bs[buf];
      #pragma unroll
      for (int kk=0; kk<32; kk++){
        const float4 a4 = *(const float4*)&Asb[kk][tr4];
        const float2 b2 = *(const float2*)&Bsb[kk][tc2];
        const float ar[4] = {a4.x, a4.y, a4.z, a4.w};
        #pragma unroll
        for (int q=0;q<4;q++){
          acc[q][0] = fmaf(ar[q], b2.x, acc[q][0]);
          acc[q][1] = fmaf(ar[q], b2.y, acc[q][1]);
        }
      }
    }
    if (more){
      int nb = buf^1;
      As[nb][kk4+0][ra]=avN.x;  As[nb][kk4+1][ra]=avN.y;  As[nb][kk4+2][ra]=avN.z;  As[nb][kk4+3][ra]=avN.w;
      As[nb][16+kk4+0][ra]=avN2.x; As[nb][16+kk4+1][ra]=avN2.y; As[nb][16+kk4+2][ra]=avN2.z; As[nb][16+kk4+3][ra]=avN2.w;
      if (t < 128){
        *(float4*)&Bs[nb][kb][c4] = bvN;
        *(float4*)&Bs[nb][kb+16][c4] = bvN2;
      }
      buf = nb;
    }
  }
  #pragma unroll
  for (int q=0;q<4;q++){
    int r = m0 + tr4 + q;
    size_t rowoff = (size_t)r*256 + n0 + tc2;
    float2 cv;
    if (P.mode == 2) cv = *(const float2*)&C[rowoff];
    float res[2];
    #pragma unroll
    for (int p=0;p<2;p++){
      int c = n0 + tc2 + p;
      size_t oi = (size_t)r*256 + c;
      float v = acc[q][p];
      if (P.mode == 1){
        v += P.E[(size_t)mat*SZF + oi] + P.t * ((chain ? P.wtt : P.wts)[c]);
        float sg = 1.0f/(1.0f + expf(-v));
        v = v * sg;
      } else if (P.mode == 2){
        float bias = (chain ? P.b2t : P.b2s)[c];
        unsigned j = ((unsigned)(mat & 3))*131072u + (unsigned)oi;
        unsigned kk0 = chain ? P.nk2 : P.nk0;
        unsigned kk1 = chain ? P.nk3 : P.nk1;
        unsigned y0, y1;
        tf2x32(kk0, kk1, 0u, j, &y0, &y1);
        float nz = bits_to_normal(y0 ^ y1);
        float cx = (p==0) ? cv.x : cv.y;
        v = cx + P.a*(v + bias) + P.bc*nz;
      } else if (P.mode == 3){
        int bb = r >> 9, s2 = r & 511;
        v += (chain ? P.b1t : P.b1s)[c]
           + P.eig[(size_t)(chain*4 + bb)*512 + s2] * ((chain ? P.wet : P.wes)[c]);
      } else if (P.mode == 4){
        v += P.recb[c];
      }
      res[p] = v;
    }
    *(float2*)&C[rowoff] = make_float2(res[0], res[1]);
  }
}

// fused cond + xinit (bit-identical to the two separate kernels)
__global__ void k_init(float* cond, float* x, const float* a, const float* v,
                       const float* xT){
  size_t i = (size_t)blockIdx.x*256 + threadIdx.x;
  size_t b = i >> 17, off = i & 131071;
  x[i] = xT[((b & 3) << 17) + off];
  if (i < 524288) cond[i] = 0.5f*(a[i] + v[i]);
}

// fused rec + copy
__global__ void k_recc(float* rec, const float* x, float* out,
                       const float* a, const float* v){
  size_t i = (size_t)blockIdx.x*256 + threadIdx.x;
  if (i < 524288) rec[i] = 0.5f*(x[i] + x[i + 524288]);
  out[524288 + i] = (i < 524288) ? a[i] : v[i - 524288];
}

// ------------------------------- host --------------------------------------
extern "C" void kernel_launch(void* const* d_in, const int* in_sizes, int n_in,
                              void* d_out, int out_size, void* d_ws, size_t ws_size,
                              hipStream_t stream){
  const float* f_audio   = (const float*)d_in[1];
  const float* f_visual  = (const float*)d_in[2];
  const float* g_speaker = (const float*)d_in[3];
  const float* g_temporal= (const float*)d_in[4];
  const float* x_T       = (const float*)d_in[6];
  const float* tsW1=(const float*)d_in[7],  *tswe=(const float*)d_in[8],
             * tswt=(const float*)d_in[9],  *tsb1=(const float*)d_in[10],
             * tsWc=(const float*)d_in[11], *tsW2=(const float*)d_in[12],
             * tsb2=(const float*)d_in[13];
  const float* ttW1=(const float*)d_in[14], *ttwe=(const float*)d_in[15],
             * ttwt=(const float*)d_in[16], *ttb1=(const float*)d_in[17],
             * ttWc=(const float*)d_in[18], *ttW2=(const float*)d_in[19],
             * ttb2=(const float*)d_in[20];
  const float* recW=(const float*)d_in[21], *recb=(const float*)d_in[22];
  float* out = (float*)d_out;

  const size_t MB = 1ull << 20;
  if (ws_size < 43*MB) return;
  bool wide = ws_size >= 80*MB;       // single-pass D&C over all 8 matrices

  char* ws = (char*)d_ws;
  double* Vh     = (double*)(ws + 0);
  double* Atail  = (double*)(ws + 16*MB);
  double* A64    = (double*)(ws + 16*MB);    // D&C overlay (after tail)
  double* Zb     = wide ? (double*)(ws + 48*MB) : (double*)(ws + 24*MB);
  double* Sm     = wide ? (double*)(ws + 64*MB) : (double*)(ws + 32*MB);
  double* smalls = (double*)(ws + 40*MB);
  unsigned* slots = (unsigned*)(smalls + 295168);
  float* Vt32_s  = (float*)(ws + 0);
  float* Vt32_t  = (float*)(ws + 8*MB);
  float* eig32   = (float*)(ws + 42*MB + 512*1024);
  double* bscr   = (double*)(ws + 42*MB + 640*1024);   // bisect scratch (~228KB)
  float* cond  = (float*)(ws + 16*MB);
  float* E     = (float*)(ws + 18*MB);
  float* xall  = (float*)(ws + 22*MB);
  float* xspec = (float*)(ws + 26*MB);
  float* hbuf  = (float*)(ws + 30*MB);

  // ---- jax.random key schedule (host, exact threefry, PARTITIONABLE) ----
  unsigned f0, f1;
  tf2x32(0u, 42u, 0u, 0u, &f0, &f1);
  unsigned s0,s1,t0,t1;
  tf2x32(f0, f1, 0u, 0u, &s0, &s1);
  tf2x32(f0, f1, 0u, 1u, &t0, &t1);
  unsigned skeys[100][2], tkeys[100][2];
  for (int k=0; k<100; k++){
    tf2x32(s0, s1, 0u, (unsigned)k, &skeys[k][0], &skeys[k][1]);
    tf2x32(t0, t1, 0u, (unsigned)k, &tkeys[k][0], &tkeys[k][1]);
  }

  hipMemsetAsync(slots, 0, 16384, stream);

  // ---- eigh: persistent head (cols 0..383) + single-block tail ----
  k_sytd2_lds<<<8*NB, 256, 0, stream>>>(g_speaker, g_temporal, Vh, smalls, slots, Atail);
  k_sy_tail<<<8, 256, 0, stream>>>(Atail, Vh, smalls);

  int npass = wide ? 1 : 2;
  int nmat  = wide ? 8 : 4;
  for (int pass=0; pass<npass; pass++){
    int sbase = wide ? 0 : 4*pass;
    k_scale<<<nmat, 256, 0, stream>>>(smalls, sbase);
    hipMemsetAsync(Zb, 0, (size_t)(wide?16:8)*MB, stream);
    hipMemsetAsync(A64, 0, (size_t)(wide?16:8)*MB, stream);
    k_leaves<<<nmat*8, 256, 0, stream>>>(smalls, Zb, sbase);
    for (int level=0; level<5; level++){
      int n = 32 << level, mpm = 512/n;
      double* src = (level & 1) ? A64 : Zb;
      double* dst = (level & 1) ? Zb  : A64;
      int split = 2 << level;
      k_deflate<<<dim3(nmat, mpm), 256, 0, stream>>>(smalls, src, bscr, level, sbase);
      k_bisect<<<dim3(nmat, mpm, split), 256, 0, stream>>>(bscr, level, split);
      k_sfin<<<dim3(nmat, mpm), 256, 0, stream>>>(smalls, Sm, bscr, level, sbase);
      k_gemm64<<<dim3(n/32, n/32, nmat*mpm), 256, 0, stream>>>(src, Sm, dst, level);
    }
    k_backq<<<dim3(nmat, 64), 256, 0, stream>>>(A64, Vh, smalls, sbase);
    k_finalize<<<dim3(nmat, 256), 256, 0, stream>>>(A64, smalls,
                                                    Vt32_s, Vt32_t, eig32, sbase);
  }

  // ---- diffusion ----
  k_init<<<4096, 256, 0, stream>>>(cond, xall, f_audio, f_visual, x_T);

  KArgs P;
  P.Vt = Vt32_s; P.Vt2 = Vt32_t;
  P.xspec = xspec; P.hbuf = hbuf; P.x = xall; P.E = E;
  P.W1s = tsW1; P.W1t = ttW1; P.W2s = tsW2; P.W2t = ttW2;
  P.b2s = tsb2; P.b2t = ttb2; P.wts = tswt; P.wtt = ttwt;
  P.b1s = tsb1; P.b1t = ttb1; P.wes = tswe; P.wet = ttwe;
  P.cond = cond; P.Wcs = tsWc; P.Wct = ttWc;
  P.eig = eig32; P.rec = xspec; P.recW = recW; P.recb = recb; P.out = out;
  P.t = 0.f; P.a = 0.f; P.bc = 0.f;
  P.nk0 = 0; P.nk1 = 0; P.nk2 = 0; P.nk3 = 0;
  P.ntx = 8;

  // mode 3: E = cond @ Wc + b1 + eig*we  (M=2048 over 2 chains)
  P.mode = 3; P.nmat = 2;
  k_gemm32<<<512, 256, 0, stream>>>(P);

  for (int k=0; k<100; k++){
    float tf = (float)(1.0 - (double)k/99.0);
    float av = (float)(pow(25.0, 2.0*(double)tf) * 0.01);
    float bcv = (float)(pow(25.0, (double)tf) * 0.1);
    P.nk0 = skeys[k][0]; P.nk1 = skeys[k][1];
    P.nk2 = tkeys[k][0]; P.nk3 = tkeys[k][1];
    P.nmat = 8;
    P.mode = 0;
    k_gemm32<<<512, 256, 0, stream>>>(P);
    P.mode = 1; P.t = tf;
    k_gemm32<<<512, 256, 0, stream>>>(P);
    P.mode = 2; P.a = av; P.bc = bcv;
    k_gemm32<<<512, 256, 0, stream>>>(P);
  }

  k_recc<<<4096, 256, 0, stream>>>(xspec, xall, out, f_audio, f_visual);
  P.mode = 4; P.nmat = 1;
  k_gemm32<<<256, 256, 0, stream>>>(P);
}